// Round 4
// baseline (521.423 us; speedup 1.0000x reference)
//
#include <hip/hip_runtime.h>

// N=32768 rows, K=8192 codes, D=256, fp32 in, int32 out.
constexpr int D_DIM   = 256;
constexpr int N_ROWS  = 32768;
constexpr int K_CODES = 8192;
// Quantized screen: dist*128 in key high bits. TQ/128 = 0.453 effective tau
// (round-10 verified tau=0.45 class; covers split error ~0.3 + quant 0.016).
constexpr unsigned TQ = 58;

typedef _Float16 f16x8  __attribute__((ext_vector_type(8)));
typedef __fp16   fp16x2 __attribute__((ext_vector_type(2)));
typedef float    f32x16 __attribute__((ext_vector_type(16)));

#define MFMA32(a, b, c) __builtin_amdgcn_mfma_f32_32x32x16_f16(a, b, c, 0, 0, 0)

// RTN split: hi = rn16(x), lo = rn16(x - hi).
__device__ __forceinline__ void cvt_rtn(const float4 a, const float4 b,
                                        uint4& hi, uint4& lo) {
    float f[8] = {a.x, a.y, a.z, a.w, b.x, b.y, b.z, b.w};
    unsigned hb[8], lb[8];
#pragma unroll
    for (int i = 0; i < 8; ++i) {
        _Float16 h = (_Float16)f[i];
        _Float16 l = (_Float16)(f[i] - (float)h);
        hb[i] = __builtin_bit_cast(unsigned short, h);
        lb[i] = __builtin_bit_cast(unsigned short, l);
    }
    hi = make_uint4(hb[0] | (hb[1] << 16), hb[2] | (hb[3] << 16),
                    hb[4] | (hb[5] << 16), hb[6] | (hb[7] << 16));
    lo = make_uint4(lb[0] | (lb[1] << 16), lb[2] | (lb[3] << 16),
                    lb[4] | (lb[5] << 16), lb[6] | (lb[7] << 16));
}

// RTZ split used by the (verified) fallback path.
__device__ __forceinline__ void cvt_granule(const float4 a, const float4 b,
                                            uint4& hi, uint4& lo) {
    fp16x2 h0 = __builtin_amdgcn_cvt_pkrtz(a.x, a.y);
    fp16x2 h1 = __builtin_amdgcn_cvt_pkrtz(a.z, a.w);
    fp16x2 h2 = __builtin_amdgcn_cvt_pkrtz(b.x, b.y);
    fp16x2 h3 = __builtin_amdgcn_cvt_pkrtz(b.z, b.w);
    fp16x2 l0 = __builtin_amdgcn_cvt_pkrtz(a.x - (float)h0.x, a.y - (float)h0.y);
    fp16x2 l1 = __builtin_amdgcn_cvt_pkrtz(a.z - (float)h1.x, a.w - (float)h1.y);
    fp16x2 l2 = __builtin_amdgcn_cvt_pkrtz(b.x - (float)h2.x, b.y - (float)h2.y);
    fp16x2 l3 = __builtin_amdgcn_cvt_pkrtz(b.z - (float)h3.x, b.w - (float)h3.y);
    hi = make_uint4(__builtin_bit_cast(unsigned, h0), __builtin_bit_cast(unsigned, h1),
                    __builtin_bit_cast(unsigned, h2), __builtin_bit_cast(unsigned, h3));
    lo = make_uint4(__builtin_bit_cast(unsigned, l0), __builtin_bit_cast(unsigned, l1),
                    __builtin_bit_cast(unsigned, l2), __builtin_bit_cast(unsigned, l3));
}

__device__ __forceinline__ void gl_lds16(const uint4* g, uint4* l) {
    __builtin_amdgcn_global_load_lds(
        (const __attribute__((address_space(1))) void*)g,
        (__attribute__((address_space(3))) void*)l, 16, 0, 0);
}

// ---------------------------------------------------------------------------
// Prep: RTN hi split of X, hi/lo split of E, esqb, counter zero.
//  X: g = rb*2048 + Lg*64 + r    (rb: 64-row block, Lg = d/8 layer 0..31)
//  E: g = cb*8192 + Lg*256 + c   (cb: 256-code tile)
// ---------------------------------------------------------------------------
__global__ __launch_bounds__(256)
void prep_kernel(const float* __restrict__ X, const float* __restrict__ E,
                 uint4* __restrict__ Xh,
                 uint4* __restrict__ Eh, uint4* __restrict__ El,
                 float* __restrict__ esqb, int* __restrict__ cnt) {
    const int tid = threadIdx.x, bid = blockIdx.x;
    if (bid < 1024) {
#pragma unroll 1
        for (int it = 0; it < 4; ++it) {
            const int gid = bid * 1024 + it * 256 + tid;
            const int rb = gid >> 11, rem = gid & 2047;
            const int Lg = rem >> 6, r = rem & 63;
            const float* p = X + (size_t)(rb * 64 + r) * D_DIM + Lg * 8;
            const float4 a = *(const float4*)p, b = *(const float4*)(p + 4);
            uint4 hi, lo; cvt_rtn(a, b, hi, lo);
            Xh[gid] = hi;
        }
    } else if (bid < 1280) {
#pragma unroll 1
        for (int it = 0; it < 4; ++it) {
            const int gid = (bid - 1024) * 1024 + it * 256 + tid;
            const int cb = gid >> 13, rem = gid & 8191;
            const int Lg = rem >> 8, c = rem & 255;
            const float* p = E + (size_t)(cb * 256 + c) * D_DIM + Lg * 8;
            const float4 a = *(const float4*)p, b = *(const float4*)(p + 4);
            uint4 hi, lo; cvt_rtn(a, b, hi, lo);
            Eh[gid] = hi; El[gid] = lo;
        }
    } else {
        if (bid == 1280 && tid == 0) *cnt = 0;
        const int t = (bid - 1280) * 256 + tid;
        const int gw = t >> 6, lane = t & 63;
        const float4 v = ((const float4*)(E + (size_t)gw * D_DIM))[lane];
        float s = v.x * v.x + v.y * v.y + v.z * v.z + v.w * v.w;
#pragma unroll
        for (int off = 32; off; off >>= 1) s += __shfl_down(s, off, 64);
        if (lane == 0) esqb[gw] = s + 1024.0f;
    }
}

// ---------------------------------------------------------------------------
// One k-step group (4 of 16 k-steps of a 256-code tile) + an interleaved
// 16-update chunk of the PREVIOUS tile's deferred epilogue. All register
// indices compile-time (S, j, u) -> no scratch (rule #20); loads are left
// to the compiler's scheduler (R1's verified pattern -- no manual rotation,
// that spilled in R3). The epilogue VALU fills the former load-wait gap and
// runs on the VALU pipe while the MFMA pipe crunches in the background.
// ---------------------------------------------------------------------------
template<int S, bool EPI>
__device__ __forceinline__ void kgroup(
    const uint4* __restrict__ Eb, const uint4 (&sXhp)[2048],
    const int l31, const int lh,
    f32x16 (&acc)[2][2], const f32x16 (&accP)[2][2],
    unsigned (&best)[2][16], unsigned (&best2)[2][16],
    const float ebp0, const float ebp1, const int codeP) {
    __builtin_amdgcn_s_setprio(1);
#pragma unroll
    for (int j = 0; j < 4; ++j) {
        const int Lg = (S * 4 + j) * 2 + lh;
        const f16x8 b0 = __builtin_bit_cast(f16x8, Eb[Lg * 256]);
        const f16x8 b1 = __builtin_bit_cast(f16x8, Eb[Lg * 256 + 32]);
        const f16x8 a0 = __builtin_bit_cast(f16x8, sXhp[Lg * 64 + l31]);
        const f16x8 a1 = __builtin_bit_cast(f16x8, sXhp[Lg * 64 + l31 + 32]);
        acc[0][0] = MFMA32(a0, b0, acc[0][0]);
        acc[0][1] = MFMA32(a0, b1, acc[0][1]);
        acc[1][0] = MFMA32(a1, b0, acc[1][0]);
        acc[1][1] = MFMA32(a1, b1, acc[1][1]);
    }
    __builtin_amdgcn_s_setprio(0);
    if constexpr (EPI) {
#pragma unroll
        for (int u = 0; u < 16; ++u) {
            const int f  = S * 16 + u;
            const int tj = f >> 5, ti = (f >> 4) & 1, r = f & 15;
            const float eb128 = tj ? ebp1 : ebp0;
            const unsigned code = (unsigned)(codeP + tj * 32);
            const float dq = fmaf(-256.0f, accP[ti][tj][r], eb128);
            const unsigned q   = (unsigned)dq;          // < 2^19
            const unsigned key = (q << 13) + code;
            // invariant best<=best2: new best2 = median(key,best,best2)
            unsigned nb2;
            asm("v_med3_u32 %0, %1, %2, %3"
                : "=v"(nb2)
                : "v"(key), "v"(best[ti][r]), "v"(best2[ti][r]));
            best2[ti][r] = nb2;
            best[ti][r]  = key < best[ti][r] ? key : best[ti][r];
        }
    }
}

// ---------------------------------------------------------------------------
// Pass 1: 1-product (xh*eh) screen, quantized-key top-2 (pure u32 lattice).
// 64-row X block (32 KB hi) staged to LDS ONCE; wave tile 64 rows x 64 codes.
// The per-tile VALU epilogue (64 lattice updates ~ as many pipe-cycles as the
// tile's 64 MFMAs) is DEFERRED one tile via ping-pong accumulators accA/accB
// and interleaved into the next tile's 4 k-step groups, so the VALU pipe and
// MFMA pipe overlap within each wave instead of alternating (R1/R2 measured
// MfmaUtil~33 + VALUBusy~36, serial phases). Static acc banks, static update
// indices -- no runtime indexing, no manual load rotation (R3 spill lesson).
// ---------------------------------------------------------------------------
__global__ __launch_bounds__(256, 2)
void vq_pass1(const uint4* __restrict__ Xh, const uint4* __restrict__ Eh,
              const float* __restrict__ esqb, uint2* __restrict__ res) {
    __shared__ uint4 sXh[2048];      // [Lg(32)][r(64)], 32 KB
    __shared__ uint2 slot[4][64];    // [wave][row], 2 KB

    const int tid  = threadIdx.x;
    const int lane = tid & 63, wv = tid >> 6;
    const int l31  = lane & 31, lh = lane >> 5;
    const int bid  = blockIdx.x;
    const int bx = bid & 511, strip = bid >> 9;   // strip-chunked: co-resident
    const int cs0 = strip * 2048;                 // blocks share one E strip

    const uint4* Xhb = Xh + bx * 2048;

    // ---- stage X hi (whole 256-d, 64 rows) once ----
#pragma unroll
    for (int i = 0; i < 8; ++i)
        gl_lds16(Xhb + i * 256 + tid, &sXh[i * 256 + (wv << 6)]);
    __syncthreads();

    unsigned best[2][16], best2[2][16];
#pragma unroll
    for (int ti = 0; ti < 2; ++ti)
#pragma unroll
        for (int r = 0; r < 16; ++r) { best[ti][r] = 0xFFFFFFFFu; best2[ti][r] = 0xFFFFFFFFu; }

    f32x16 accA[2][2], accB[2][2];

    auto zacc = [](f32x16 (&a)[2][2]) {
#pragma unroll
        for (int ti = 0; ti < 2; ++ti)
#pragma unroll
            for (int tj = 0; tj < 2; ++tj)
#pragma unroll
                for (int i = 0; i < 16; ++i) a[ti][tj][i] = 0.0f;
    };

    // E base for this wave's 64-code column of tile 0 (lane-contiguous 16 B)
    const uint4* __restrict__ Eb = Eh + (size_t)(strip * 8) * 8192 + wv * 64 + l31;
    int codeP = cs0 + wv * 64 + l31;            // tile-0 per-lane code base
    float ebP0 = esqb[codeP] * 128.0f;          // tile-0 (e_sq+1024)*128
    float ebP1 = esqb[codeP + 32] * 128.0f;

    // ---- tile 0: k-loop only (no deferred epilogue yet) ----
    zacc(accA);
    kgroup<0, false>(Eb, sXh, l31, lh, accA, accA, best, best2, 0.f, 0.f, 0);
    kgroup<1, false>(Eb, sXh, l31, lh, accA, accA, best, best2, 0.f, 0.f, 0);
    kgroup<2, false>(Eb, sXh, l31, lh, accA, accA, best, best2, 0.f, 0.f, 0);
    kgroup<3, false>(Eb, sXh, l31, lh, accA, accA, best, best2, 0.f, 0.f, 0);

    // ---- tiles 1..6 in ping-pong pairs ----
#pragma unroll 1
    for (int p = 0; p < 3; ++p) {
        // odd tile (2p+1) -> accB, interleaved epilogue of accA (tile 2p)
        Eb += 8192;
        float ebc0 = esqb[codeP + 256] * 128.0f;   // this tile's eb (for next)
        float ebc1 = esqb[codeP + 288] * 128.0f;
        zacc(accB);
        kgroup<0, true>(Eb, sXh, l31, lh, accB, accA, best, best2, ebP0, ebP1, codeP);
        kgroup<1, true>(Eb, sXh, l31, lh, accB, accA, best, best2, ebP0, ebP1, codeP);
        kgroup<2, true>(Eb, sXh, l31, lh, accB, accA, best, best2, ebP0, ebP1, codeP);
        kgroup<3, true>(Eb, sXh, l31, lh, accB, accA, best, best2, ebP0, ebP1, codeP);
        ebP0 = ebc0; ebP1 = ebc1; codeP += 256;

        // even tile (2p+2) -> accA, interleaved epilogue of accB (tile 2p+1)
        Eb += 8192;
        ebc0 = esqb[codeP + 256] * 128.0f;
        ebc1 = esqb[codeP + 288] * 128.0f;
        zacc(accA);
        kgroup<0, true>(Eb, sXh, l31, lh, accA, accB, best, best2, ebP0, ebP1, codeP);
        kgroup<1, true>(Eb, sXh, l31, lh, accA, accB, best, best2, ebP0, ebP1, codeP);
        kgroup<2, true>(Eb, sXh, l31, lh, accA, accB, best, best2, ebP0, ebP1, codeP);
        kgroup<3, true>(Eb, sXh, l31, lh, accA, accB, best, best2, ebP0, ebP1, codeP);
        ebP0 = ebc0; ebP1 = ebc1; codeP += 256;
    }

    // ---- tile 7 -> accB, interleaved epilogue of accA (tile 6) ----
    Eb += 8192;
    {
        const float e70 = esqb[codeP + 256] * 128.0f;
        const float e71 = esqb[codeP + 288] * 128.0f;
        zacc(accB);
        kgroup<0, true>(Eb, sXh, l31, lh, accB, accA, best, best2, ebP0, ebP1, codeP);
        kgroup<1, true>(Eb, sXh, l31, lh, accB, accA, best, best2, ebP0, ebP1, codeP);
        kgroup<2, true>(Eb, sXh, l31, lh, accB, accA, best, best2, ebP0, ebP1, codeP);
        kgroup<3, true>(Eb, sXh, l31, lh, accB, accA, best, best2, ebP0, ebP1, codeP);
        codeP += 256;

        // ---- final (non-deferred) epilogue: tile 7 ----
#pragma unroll
        for (int tj = 0; tj < 2; ++tj) {
            const unsigned code = (unsigned)(codeP + tj * 32);
            const float eb128 = tj ? e71 : e70;
#pragma unroll
            for (int ti = 0; ti < 2; ++ti)
#pragma unroll
                for (int r = 0; r < 16; ++r) {
                    const float dq = fmaf(-256.0f, accB[ti][tj][r], eb128);
                    const unsigned q   = (unsigned)dq;
                    const unsigned key = (q << 13) + code;
                    unsigned nb2;
                    asm("v_med3_u32 %0, %1, %2, %3"
                        : "=v"(nb2)
                        : "v"(key), "v"(best[ti][r]), "v"(best2[ti][r]));
                    best2[ti][r] = nb2;
                    best[ti][r]  = key < best[ti][r] ? key : best[ti][r];
                }
        }
    }

    // butterfly over 32 code-lanes (exact top-2 merge, u32)
#pragma unroll
    for (int ti = 0; ti < 2; ++ti)
#pragma unroll
        for (int r = 0; r < 16; ++r) {
            unsigned b1 = best[ti][r], b2 = best2[ti][r];
#pragma unroll
            for (int m = 16; m >= 1; m >>= 1) {
                const unsigned o1 = (unsigned)__shfl_xor((int)b1, m, 32);
                const unsigned o2 = (unsigned)__shfl_xor((int)b2, m, 32);
                const unsigned t  = b1 > o1 ? b1 : o1;
                b1 = b1 < o1 ? b1 : o1;
                const unsigned m2 = b2 < o2 ? b2 : o2;
                b2 = m2 < t ? m2 : t;
            }
            if (l31 == 0) {
                const int row = ti * 32 + (r & 3) + 8 * (r >> 2) + 4 * lh;
                slot[wv][row] = make_uint2(b1, b2);
            }
        }

    __syncthreads();
    if (tid < 64) {
        const uint2 A = slot[0][tid];
        unsigned b1 = A.x, b2 = A.y;
#pragma unroll
        for (int s = 1; s < 4; ++s) {
            const uint2 B = slot[s][tid];
            const unsigned t  = b1 > B.x ? b1 : B.x;
            b1 = b1 < B.x ? b1 : B.x;
            const unsigned m2 = b2 < B.y ? b2 : B.y;
            b2 = m2 < t ? m2 : t;
        }
        res[(size_t)strip * N_ROWS + bx * 64 + tid] = make_uint2(b1, b2);
    }
}

// ---------------------------------------------------------------------------
// Merge 4 strips (exact keyed top-2): clean rows -> out; ambiguous -> list.
// ---------------------------------------------------------------------------
__global__ void merge_kernel(const uint2* __restrict__ res,
                             unsigned long long* __restrict__ res0,
                             int* __restrict__ out,
                             int* __restrict__ cnt, int* __restrict__ list) {
    const int row = blockIdx.x * 256 + threadIdx.x;
    unsigned b1 = 0xFFFFFFFFu, b2 = 0xFFFFFFFFu;
#pragma unroll
    for (int s = 0; s < 4; ++s) {
        const uint2 v = res[(size_t)s * N_ROWS + row];
        const unsigned t = b1 > v.x ? b1 : v.x;
        b1 = b1 < v.x ? b1 : v.x;
        const unsigned m2 = b2 < v.y ? b2 : v.y;
        b2 = m2 < t ? m2 : t;
    }
    out[row] = (int)(b1 & 8191u);
    if ((b2 >> 13) - (b1 >> 13) < TQ) {
        const int p = atomicAdd(cnt, 1);
        list[p] = row;
        res0[row] = ~0ull;
    }
}

// ---------------------------------------------------------------------------
// Refine: flagged rows, exact 3-product over all codes (verified structure).
// Block = 32 gathered rows x 1024-code strip (grid 1024 x 8, uniform exit).
// A rows converted from raw fp32 on the fly (same RTN split as prep).
// ---------------------------------------------------------------------------
__global__ __launch_bounds__(256, 1)
void refine_kernel(const float* __restrict__ X,
                   const uint4* __restrict__ Eh, const uint4* __restrict__ El,
                   const float* __restrict__ esqb, const int* __restrict__ cnt,
                   const int* __restrict__ list, unsigned long long* __restrict__ res0) {
    __shared__ int  rows_s[32];
    __shared__ uint4 sAh[1024], sAl[1024];   // 32 KB

    const int n = *cnt;
    const int base = blockIdx.x * 32;
    if (base >= n) return;                   // block-uniform
    const int tid = threadIdx.x;
    if (tid < 32) { const int j = base + tid; rows_s[tid] = list[j < n ? j : base]; }
    __syncthreads();

    // gather + split A: granule slot Lg (0..31) x row slot rr (0..31)
#pragma unroll
    for (int jj = 0; jj < 4; ++jj) {
        const int gg = jj * 256 + tid, Lg = gg >> 5, rr = gg & 31;
        const int row = rows_s[rr];
        const float* p = X + (size_t)row * D_DIM + Lg * 8;
        const float4 a = *(const float4*)p, b = *(const float4*)(p + 4);
        uint4 hi, lo; cvt_rtn(a, b, hi, lo);
        sAh[Lg * 32 + rr] = hi; sAl[Lg * 32 + rr] = lo;
    }
    __syncthreads();

    const int lane = tid & 63, wv = tid >> 6, l31 = lane & 31, lh = lane >> 5;
    const int cbase = blockIdx.y * 1024 + wv * 256;

    float bestv[16]; int besti[16];
#pragma unroll
    for (int r = 0; r < 16; ++r) { bestv[r] = 3.0e38f; besti[r] = 0; }

#pragma unroll 1
    for (int ps = 0; ps < 2; ++ps) {         // 2 passes of 128 codes
        const int c0 = cbase + ps * 128;
        f32x16 acc[4];
#pragma unroll
        for (int tj = 0; tj < 4; ++tj)
#pragma unroll
            for (int i = 0; i < 16; ++i) acc[tj][i] = 0.0f;

#pragma unroll
        for (int ks = 0; ks < 16; ++ks) {
            const int Lg = ks * 2 + lh;
            f16x8 b0[4], b1[4];
#pragma unroll
            for (int tj = 0; tj < 4; ++tj) {
                const int c = c0 + tj * 32 + l31;
                const int eg = (c >> 8) * 8192 + Lg * 256 + (c & 255);
                b0[tj] = __builtin_bit_cast(f16x8, Eh[eg]);
                b1[tj] = __builtin_bit_cast(f16x8, El[eg]);
            }
            const f16x8 a0 = __builtin_bit_cast(f16x8, sAh[Lg * 32 + l31]);
            const f16x8 a1 = __builtin_bit_cast(f16x8, sAl[Lg * 32 + l31]);
#pragma unroll
            for (int tj = 0; tj < 4; ++tj) acc[tj] = MFMA32(a1, b0[tj], acc[tj]);
#pragma unroll
            for (int tj = 0; tj < 4; ++tj) acc[tj] = MFMA32(a0, b1[tj], acc[tj]);
#pragma unroll
            for (int tj = 0; tj < 4; ++tj) acc[tj] = MFMA32(a0, b0[tj], acc[tj]);
        }

#pragma unroll
        for (int tj = 0; tj < 4; ++tj) {
            const int c = c0 + tj * 32 + l31;
            const float eb = esqb[c];
#pragma unroll
            for (int r = 0; r < 16; ++r) {
                const float dv = fmaf(-2.0f, acc[tj][r], eb);
                if (dv < bestv[r]) { bestv[r] = dv; besti[r] = c; }
            }
        }
    }

#pragma unroll
    for (int r = 0; r < 16; ++r) {
        float v = bestv[r]; int bi = besti[r];
#pragma unroll
        for (int m = 16; m >= 1; m >>= 1) {
            const float ov = __shfl_xor(v, m, 32);
            const int   oi = __shfl_xor(bi, m, 32);
            if (ov < v || (ov == v && oi < bi)) { v = ov; bi = oi; }
        }
        if (l31 == 0) {
            const int rl = (r & 3) + 8 * (r >> 2) + 4 * lh;   // 0..31
            atomicMin(&res0[rows_s[rl]],
                      ((unsigned long long)__float_as_uint(v) << 32) | (unsigned)bi);
        }
    }
}

// ---------------------------------------------------------------------------
__global__ void finalize_kernel(const unsigned long long* __restrict__ res0,
                                const int* __restrict__ cnt, const int* __restrict__ list,
                                int* __restrict__ out) {
    const int i = blockIdx.x * 256 + threadIdx.x;
    if (i < *cnt) {
        const int row = list[i];
        out[row] = (int)(res0[row] & 0xFFFFFFFFull);
    }
}

// ---------------------------------------------------------------------------
// Fallback (round-4 verified): in-loop split, for small ws_size.
// ---------------------------------------------------------------------------
__global__ void prologue_fb(const float* __restrict__ E, float* __restrict__ esqb,
                            unsigned long long* __restrict__ packed) {
    const int t = blockIdx.x * 256 + threadIdx.x;
    if (t < N_ROWS) packed[t] = ~0ull;
    const int gw = t >> 6, lane = t & 63;
    const float4 v = ((const float4*)(E + (size_t)gw * D_DIM))[lane];
    float s = v.x * v.x + v.y * v.y + v.z * v.z + v.w * v.w;
#pragma unroll
    for (int off = 32; off; off >>= 1) s += __shfl_down(s, off, 64);
    if (lane == 0) esqb[gw] = s + 1024.0f;
}

__global__ __launch_bounds__(256, 2)
void vq_mfma_fallback(const float* __restrict__ X, const float* __restrict__ E,
                      const float* __restrict__ esqb,
                      unsigned long long* __restrict__ packed) {
    __shared__ uint4 fXh[128 * 8], fXl[128 * 8];
    __shared__ uint4 fEh[128 * 8], fEl[128 * 8];
    __shared__ float fEsq[2048];

    const int tid  = threadIdx.x;
    const int lane = tid & 63;
    const int wv   = tid >> 6;
    const int wr   = wv >> 1, wc = wv & 1;
    const int l31  = lane & 31;
    const int lh   = lane >> 5;
    const int row0 = blockIdx.x * 128;
    const int cs0  = blockIdx.y * 2048;

#pragma unroll
    for (int i = 0; i < 8; ++i) fEsq[tid + 256 * i] = esqb[cs0 + tid + 256 * i];

    const int sr = tid >> 3, sg = tid & 7;

    float best[2][16]; int bidx[2][16];
#pragma unroll
    for (int ti = 0; ti < 2; ++ti)
#pragma unroll
        for (int r = 0; r < 16; ++r) { best[ti][r] = 3.0e38f; bidx[ti][r] = 0; }

    f32x16 acc[2][2];

#pragma unroll 1
    for (int ct = 0; ct < 16; ++ct) {
#pragma unroll
        for (int ti = 0; ti < 2; ++ti)
#pragma unroll
            for (int tj = 0; tj < 2; ++tj)
#pragma unroll
                for (int i = 0; i < 16; ++i) acc[ti][tj][i] = 0.0f;

#pragma unroll 1
        for (int dc = 0; dc < 4; ++dc) {
            __syncthreads();
#pragma unroll
            for (int i = 0; i < 4; ++i) {
                const int r = 32 * i + sr;
                const float* p = X + (size_t)(row0 + r) * D_DIM + dc * 64 + sg * 8;
                const float4 a = *(const float4*)p, b = *(const float4*)(p + 4);
                uint4 hi, lo; cvt_granule(a, b, hi, lo);
                const int o = r * 8 + (sg ^ (r & 7));
                fXh[o] = hi; fXl[o] = lo;
            }
#pragma unroll
            for (int i = 0; i < 4; ++i) {
                const int r = 32 * i + sr;
                const float* p = E + (size_t)(cs0 + ct * 128 + r) * D_DIM + dc * 64 + sg * 8;
                const float4 a = *(const float4*)p, b = *(const float4*)(p + 4);
                uint4 hi, lo; cvt_granule(a, b, hi, lo);
                const int o = r * 8 + (sg ^ (r & 7));
                fEh[o] = hi; fEl[o] = lo;
            }
            __syncthreads();

#pragma unroll
            for (int s = 0; s < 4; ++s) {
                const int gi = s * 2 + lh;
                f16x8 axh[2], axl[2], beh[2], bel[2];
#pragma unroll
                for (int ti = 0; ti < 2; ++ti) {
                    const int r = wr * 64 + ti * 32 + l31;
                    const int o = r * 8 + (gi ^ (r & 7));
                    axh[ti] = __builtin_bit_cast(f16x8, fXh[o]);
                    axl[ti] = __builtin_bit_cast(f16x8, fXl[o]);
                }
#pragma unroll
                for (int tj = 0; tj < 2; ++tj) {
                    const int c = wc * 64 + tj * 32 + l31;
                    const int o = c * 8 + (gi ^ (c & 7));
                    beh[tj] = __builtin_bit_cast(f16x8, fEh[o]);
                    bel[tj] = __builtin_bit_cast(f16x8, fEl[o]);
                }
#pragma unroll
                for (int ti = 0; ti < 2; ++ti)
#pragma unroll
                    for (int tj = 0; tj < 2; ++tj) {
                        acc[ti][tj] = MFMA32(axl[ti], beh[tj], acc[ti][tj]);
                        acc[ti][tj] = MFMA32(axh[ti], bel[tj], acc[ti][tj]);
                        acc[ti][tj] = MFMA32(axh[ti], beh[tj], acc[ti][tj]);
                    }
            }
        }

#pragma unroll
        for (int tj = 0; tj < 2; ++tj) {
            const int cloc = ct * 128 + wc * 64 + tj * 32 + l31;
            const float eb = fEsq[cloc];
            const int  code = cs0 + cloc;
#pragma unroll
            for (int ti = 0; ti < 2; ++ti)
#pragma unroll
                for (int r = 0; r < 16; ++r) {
                    const float dv = fmaf(-2.0f, acc[ti][tj][r], eb);
                    if (dv < best[ti][r]) { best[ti][r] = dv; bidx[ti][r] = code; }
                }
        }
    }

#pragma unroll
    for (int ti = 0; ti < 2; ++ti)
#pragma unroll
        for (int r = 0; r < 16; ++r) {
            float b = best[ti][r]; int bi = bidx[ti][r];
#pragma unroll
            for (int m = 16; m >= 1; m >>= 1) {
                const float ov = __shfl_xor(b, m, 32);
                const int   oi = __shfl_xor(bi, m, 32);
                if (ov < b || (ov == b && oi < bi)) { b = ov; bi = oi; }
            }
            if (l31 == 0) {
                const int row = row0 + wr * 64 + ti * 32 + (r & 3) + 8 * (r >> 2) + 4 * lh;
                const unsigned long long p =
                    ((unsigned long long)__float_as_uint(b) << 32) | (unsigned)bi;
                atomicMin(&packed[row], p);
            }
        }
}

__global__ void finish_fb(const unsigned long long* __restrict__ packed,
                          int* __restrict__ out) {
    const int i = blockIdx.x * 256 + threadIdx.x;
    out[i] = (int)(unsigned)(packed[i] & 0xffffffffull);
}

// ---------------------------------------------------------------------------
extern "C" void kernel_launch(void* const* d_in, const int* in_sizes, int n_in,
                              void* d_out, int out_size, void* d_ws, size_t ws_size,
                              hipStream_t stream) {
    const float* X = (const float*)d_in[0];    // [32768, 256]
    const float* E = (const float*)d_in[1];    // [8192, 256]
    char* ws = (char*)d_ws;
    int* out = (int*)d_out;

    float* esqb = (float*)ws;                                    // 32 KB @ 0
    uint2* res  = (uint2*)(ws + 32768);                          // 1 MB (4 strips)
    unsigned long long* res0 = (unsigned long long*)(ws + 1081344); // 256 KB
    int* cnt  = (int*)(ws + 1343488);                            // 16 B
    int* list = (int*)(ws + 1343504);                            // 128 KB
    const size_t base = 1572864;                                 // 1.5 MB
    const size_t szX  = (size_t)N_ROWS * D_DIM * 2;              // 16 MB (hi only)
    const size_t szE  = (size_t)K_CODES * D_DIM * 2;             // 4 MB per half
    const size_t need = base + szX + 2 * szE;                    // ~25.5 MB

    if (ws_size >= need) {
        uint4* Xh = (uint4*)(ws + base);
        uint4* Eh = (uint4*)(ws + base + szX);
        uint4* El = (uint4*)(ws + base + szX + szE);
        prep_kernel<<<dim3(3328), dim3(256), 0, stream>>>(X, E, Xh, Eh, El, esqb, cnt);
        vq_pass1<<<dim3(2048), dim3(256), 0, stream>>>(Xh, Eh, esqb, res);
        merge_kernel<<<dim3(N_ROWS / 256), dim3(256), 0, stream>>>(res, res0, out, cnt, list);
        refine_kernel<<<dim3(1024, 8), dim3(256), 0, stream>>>(X, Eh, El, esqb,
                                                               cnt, list, res0);
        finalize_kernel<<<dim3(N_ROWS / 256), dim3(256), 0, stream>>>(res0, cnt, list, out);
    } else {
        unsigned long long* packed = (unsigned long long*)(ws + 32768);
        prologue_fb<<<dim3(2048), dim3(256), 0, stream>>>(E, esqb, packed);
        vq_mfma_fallback<<<dim3(N_ROWS / 128, 4), dim3(256), 0, stream>>>(X, E, esqb, packed);
        finish_fb<<<dim3(N_ROWS / 256), dim3(256), 0, stream>>>(packed, out);
    }
}

// Round 5
// 328.615 us; speedup vs baseline: 1.5867x; 1.5867x over previous
//
#include <hip/hip_runtime.h>

// N=32768 rows, K=8192 codes, D=256, fp32 in, int32 out.
constexpr int D_DIM   = 256;
constexpr int N_ROWS  = 32768;
constexpr int K_CODES = 8192;
// Quantized screen: dist*128 in key high bits. TQ/128 = 0.453 effective tau
// (round-10 verified tau=0.45 class; covers split error ~0.3 + quant 0.016).
constexpr unsigned TQ = 58;

typedef _Float16 f16x8  __attribute__((ext_vector_type(8)));
typedef __fp16   fp16x2 __attribute__((ext_vector_type(2)));
typedef float    f32x16 __attribute__((ext_vector_type(16)));

#define MFMA32(a, b, c) __builtin_amdgcn_mfma_f32_32x32x16_f16(a, b, c, 0, 0, 0)

// RTN split: hi = rn16(x), lo = rn16(x - hi).
__device__ __forceinline__ void cvt_rtn(const float4 a, const float4 b,
                                        uint4& hi, uint4& lo) {
    float f[8] = {a.x, a.y, a.z, a.w, b.x, b.y, b.z, b.w};
    unsigned hb[8], lb[8];
#pragma unroll
    for (int i = 0; i < 8; ++i) {
        _Float16 h = (_Float16)f[i];
        _Float16 l = (_Float16)(f[i] - (float)h);
        hb[i] = __builtin_bit_cast(unsigned short, h);
        lb[i] = __builtin_bit_cast(unsigned short, l);
    }
    hi = make_uint4(hb[0] | (hb[1] << 16), hb[2] | (hb[3] << 16),
                    hb[4] | (hb[5] << 16), hb[6] | (hb[7] << 16));
    lo = make_uint4(lb[0] | (lb[1] << 16), lb[2] | (lb[3] << 16),
                    lb[4] | (lb[5] << 16), lb[6] | (lb[7] << 16));
}

// RTZ split used by the (verified) fallback path.
__device__ __forceinline__ void cvt_granule(const float4 a, const float4 b,
                                            uint4& hi, uint4& lo) {
    fp16x2 h0 = __builtin_amdgcn_cvt_pkrtz(a.x, a.y);
    fp16x2 h1 = __builtin_amdgcn_cvt_pkrtz(a.z, a.w);
    fp16x2 h2 = __builtin_amdgcn_cvt_pkrtz(b.x, b.y);
    fp16x2 h3 = __builtin_amdgcn_cvt_pkrtz(b.z, b.w);
    fp16x2 l0 = __builtin_amdgcn_cvt_pkrtz(a.x - (float)h0.x, a.y - (float)h0.y);
    fp16x2 l1 = __builtin_amdgcn_cvt_pkrtz(a.z - (float)h1.x, a.w - (float)h1.y);
    fp16x2 l2 = __builtin_amdgcn_cvt_pkrtz(b.x - (float)h2.x, b.y - (float)h2.y);
    fp16x2 l3 = __builtin_amdgcn_cvt_pkrtz(b.z - (float)h3.x, b.w - (float)h3.y);
    hi = make_uint4(__builtin_bit_cast(unsigned, h0), __builtin_bit_cast(unsigned, h1),
                    __builtin_bit_cast(unsigned, h2), __builtin_bit_cast(unsigned, h3));
    lo = make_uint4(__builtin_bit_cast(unsigned, l0), __builtin_bit_cast(unsigned, l1),
                    __builtin_bit_cast(unsigned, l2), __builtin_bit_cast(unsigned, l3));
}

__device__ __forceinline__ void gl_lds16(const uint4* g, uint4* l) {
    __builtin_amdgcn_global_load_lds(
        (const __attribute__((address_space(1))) void*)g,
        (__attribute__((address_space(3))) void*)l, 16, 0, 0);
}

// ---------------------------------------------------------------------------
// Prep: RTN hi split of X, hi/lo split of E, esqb, counter zero.
//  X: g = rb*2048 + Lg*64 + r    (rb: 64-row block, Lg = d/8 layer 0..31)
//  E: g = cb*8192 + Lg*256 + c   (cb: 256-code tile)
// ---------------------------------------------------------------------------
__global__ __launch_bounds__(256)
void prep_kernel(const float* __restrict__ X, const float* __restrict__ E,
                 uint4* __restrict__ Xh,
                 uint4* __restrict__ Eh, uint4* __restrict__ El,
                 float* __restrict__ esqb, int* __restrict__ cnt) {
    const int tid = threadIdx.x, bid = blockIdx.x;
    if (bid < 1024) {
#pragma unroll 1
        for (int it = 0; it < 4; ++it) {
            const int gid = bid * 1024 + it * 256 + tid;
            const int rb = gid >> 11, rem = gid & 2047;
            const int Lg = rem >> 6, r = rem & 63;
            const float* p = X + (size_t)(rb * 64 + r) * D_DIM + Lg * 8;
            const float4 a = *(const float4*)p, b = *(const float4*)(p + 4);
            uint4 hi, lo; cvt_rtn(a, b, hi, lo);
            Xh[gid] = hi;
        }
    } else if (bid < 1280) {
#pragma unroll 1
        for (int it = 0; it < 4; ++it) {
            const int gid = (bid - 1024) * 1024 + it * 256 + tid;
            const int cb = gid >> 13, rem = gid & 8191;
            const int Lg = rem >> 8, c = rem & 255;
            const float* p = E + (size_t)(cb * 256 + c) * D_DIM + Lg * 8;
            const float4 a = *(const float4*)p, b = *(const float4*)(p + 4);
            uint4 hi, lo; cvt_rtn(a, b, hi, lo);
            Eh[gid] = hi; El[gid] = lo;
        }
    } else {
        if (bid == 1280 && tid == 0) *cnt = 0;
        const int t = (bid - 1280) * 256 + tid;
        const int gw = t >> 6, lane = t & 63;
        const float4 v = ((const float4*)(E + (size_t)gw * D_DIM))[lane];
        float s = v.x * v.x + v.y * v.y + v.z * v.z + v.w * v.w;
#pragma unroll
        for (int off = 32; off; off >>= 1) s += __shfl_down(s, off, 64);
        if (lane == 0) esqb[gw] = s + 1024.0f;
    }
}

// ---------------------------------------------------------------------------
// Pass 1: 1-product (xh*eh) screen, quantized-key top-2 (pure u32 lattice).
// 64-row X block (32 KB hi) staged to LDS ONCE; 34 KB LDS -> 3 blocks/CU.
// Wave tile 64 rows x 64 codes (R1-verified low-pressure shape: acc=64 AGPR,
// lattice=64 VGPR, VGPR_Count 84 vs cap ~170 at launch_bounds(256,3)).
// Delta vs R1: k-loop unroll 4 -> 8 (compiler-scheduled, NO manual rotation
// -- R3/R4 proved manual rotation / dual acc banks spill to scratch) so up
// to 16 E-loads (~64 regs) ride in flight per body, doubling latency cover
// at the body boundary; esqb epilogue operands hoisted above the k-loop.
// ---------------------------------------------------------------------------
__global__ __launch_bounds__(256, 3)
void vq_pass1(const uint4* __restrict__ Xh, const uint4* __restrict__ Eh,
              const float* __restrict__ esqb, uint2* __restrict__ res) {
    __shared__ uint4 sXh[2048];      // [Lg(32)][r(64)], 32 KB
    __shared__ uint2 slot[4][64];    // [wave][row], 2 KB

    const int tid  = threadIdx.x;
    const int lane = tid & 63, wv = tid >> 6;
    const int l31  = lane & 31, lh = lane >> 5;
    const int bid  = blockIdx.x;
    const int bx = bid & 511, strip = bid >> 9;   // strip-chunked: co-resident
    const int cs0 = strip * 2048;                 // blocks share one E strip

    const uint4* Xhb = Xh + bx * 2048;

    // ---- stage X hi (whole 256-d, 64 rows) once ----
#pragma unroll
    for (int i = 0; i < 8; ++i)
        gl_lds16(Xhb + i * 256 + tid, &sXh[i * 256 + (wv << 6)]);
    __syncthreads();

    unsigned best[2][16], best2[2][16];
#pragma unroll
    for (int ti = 0; ti < 2; ++ti)
#pragma unroll
        for (int r = 0; r < 16; ++r) { best[ti][r] = 0xFFFFFFFFu; best2[ti][r] = 0xFFFFFFFFu; }

    f32x16 acc[2][2];

#pragma unroll 1
    for (int ct = 0; ct < 8; ++ct) {        // 256-code tiles
        // E base for this wave's 64-code column (lane-contiguous granules)
        const uint4* __restrict__ Eb =
            Eh + (size_t)(strip * 8 + ct) * 8192 + wv * 64 + l31;

        // hoist epilogue operands: no VMEM wait at epilogue start
        const int code0 = cs0 + ct * 256 + wv * 64 + l31;
        const float eb0 = esqb[code0] * 128.0f;        // (e_sq+1024)*128
        const float eb1 = esqb[code0 + 32] * 128.0f;

#pragma unroll
        for (int ti = 0; ti < 2; ++ti)
#pragma unroll
            for (int tj = 0; tj < 2; ++tj)
#pragma unroll
                for (int i = 0; i < 16; ++i) acc[ti][tj][i] = 0.0f;

#pragma unroll 8
        for (int k = 0; k < 16; ++k) {       // K-steps of 16 dims, barrier-free
            const int Lg = k * 2 + lh;
            const f16x8 b0 = __builtin_bit_cast(f16x8, Eb[Lg * 256]);
            const f16x8 b1 = __builtin_bit_cast(f16x8, Eb[Lg * 256 + 32]);
            const f16x8 a0 = __builtin_bit_cast(f16x8, sXh[Lg * 64 + l31]);
            const f16x8 a1 = __builtin_bit_cast(f16x8, sXh[Lg * 64 + l31 + 32]);
            acc[0][0] = MFMA32(a0, b0, acc[0][0]);
            acc[0][1] = MFMA32(a0, b1, acc[0][1]);
            acc[1][0] = MFMA32(a1, b0, acc[1][0]);
            acc[1][1] = MFMA32(a1, b1, acc[1][1]);
        }

        // epilogue: keyed top-2 lattice update (order-free)
#pragma unroll
        for (int tj = 0; tj < 2; ++tj) {
            const unsigned code = (unsigned)(code0 + tj * 32);
            const float eb128 = tj ? eb1 : eb0;
#pragma unroll
            for (int ti = 0; ti < 2; ++ti)
#pragma unroll
                for (int r = 0; r < 16; ++r) {
                    const float dq = fmaf(-256.0f, acc[ti][tj][r], eb128);
                    const unsigned q   = (unsigned)dq;          // < 2^19
                    const unsigned key = (q << 13) + code;
                    // invariant best<=best2: new best2 = median(key,best,best2)
                    unsigned nb2;
                    asm("v_med3_u32 %0, %1, %2, %3"
                        : "=v"(nb2)
                        : "v"(key), "v"(best[ti][r]), "v"(best2[ti][r]));
                    best2[ti][r] = nb2;
                    best[ti][r]  = key < best[ti][r] ? key : best[ti][r];
                }
        }
    }

    // butterfly over 32 code-lanes (exact top-2 merge, u32)
#pragma unroll
    for (int ti = 0; ti < 2; ++ti)
#pragma unroll
        for (int r = 0; r < 16; ++r) {
            unsigned b1 = best[ti][r], b2 = best2[ti][r];
#pragma unroll
            for (int m = 16; m >= 1; m >>= 1) {
                const unsigned o1 = (unsigned)__shfl_xor((int)b1, m, 32);
                const unsigned o2 = (unsigned)__shfl_xor((int)b2, m, 32);
                const unsigned t  = b1 > o1 ? b1 : o1;
                b1 = b1 < o1 ? b1 : o1;
                const unsigned m2 = b2 < o2 ? b2 : o2;
                b2 = m2 < t ? m2 : t;
            }
            if (l31 == 0) {
                const int row = ti * 32 + (r & 3) + 8 * (r >> 2) + 4 * lh;
                slot[wv][row] = make_uint2(b1, b2);
            }
        }

    __syncthreads();
    if (tid < 64) {
        const uint2 A = slot[0][tid];
        unsigned b1 = A.x, b2 = A.y;
#pragma unroll
        for (int s = 1; s < 4; ++s) {
            const uint2 B = slot[s][tid];
            const unsigned t  = b1 > B.x ? b1 : B.x;
            b1 = b1 < B.x ? b1 : B.x;
            const unsigned m2 = b2 < B.y ? b2 : B.y;
            b2 = m2 < t ? m2 : t;
        }
        res[(size_t)strip * N_ROWS + bx * 64 + tid] = make_uint2(b1, b2);
    }
}

// ---------------------------------------------------------------------------
// Merge 4 strips (exact keyed top-2): clean rows -> out; ambiguous -> list.
// ---------------------------------------------------------------------------
__global__ void merge_kernel(const uint2* __restrict__ res,
                             unsigned long long* __restrict__ res0,
                             int* __restrict__ out,
                             int* __restrict__ cnt, int* __restrict__ list) {
    const int row = blockIdx.x * 256 + threadIdx.x;
    unsigned b1 = 0xFFFFFFFFu, b2 = 0xFFFFFFFFu;
#pragma unroll
    for (int s = 0; s < 4; ++s) {
        const uint2 v = res[(size_t)s * N_ROWS + row];
        const unsigned t = b1 > v.x ? b1 : v.x;
        b1 = b1 < v.x ? b1 : v.x;
        const unsigned m2 = b2 < v.y ? b2 : v.y;
        b2 = m2 < t ? m2 : t;
    }
    out[row] = (int)(b1 & 8191u);
    if ((b2 >> 13) - (b1 >> 13) < TQ) {
        const int p = atomicAdd(cnt, 1);
        list[p] = row;
        res0[row] = ~0ull;
    }
}

// ---------------------------------------------------------------------------
// Refine: flagged rows, exact 3-product over all codes (verified structure).
// Block = 32 gathered rows x 1024-code strip (grid 1024 x 8, uniform exit).
// A rows converted from raw fp32 on the fly (same RTN split as prep).
// ---------------------------------------------------------------------------
__global__ __launch_bounds__(256, 1)
void refine_kernel(const float* __restrict__ X,
                   const uint4* __restrict__ Eh, const uint4* __restrict__ El,
                   const float* __restrict__ esqb, const int* __restrict__ cnt,
                   const int* __restrict__ list, unsigned long long* __restrict__ res0) {
    __shared__ int  rows_s[32];
    __shared__ uint4 sAh[1024], sAl[1024];   // 32 KB

    const int n = *cnt;
    const int base = blockIdx.x * 32;
    if (base >= n) return;                   // block-uniform
    const int tid = threadIdx.x;
    if (tid < 32) { const int j = base + tid; rows_s[tid] = list[j < n ? j : base]; }
    __syncthreads();

    // gather + split A: granule slot Lg (0..31) x row slot rr (0..31)
#pragma unroll
    for (int jj = 0; jj < 4; ++jj) {
        const int gg = jj * 256 + tid, Lg = gg >> 5, rr = gg & 31;
        const int row = rows_s[rr];
        const float* p = X + (size_t)row * D_DIM + Lg * 8;
        const float4 a = *(const float4*)p, b = *(const float4*)(p + 4);
        uint4 hi, lo; cvt_rtn(a, b, hi, lo);
        sAh[Lg * 32 + rr] = hi; sAl[Lg * 32 + rr] = lo;
    }
    __syncthreads();

    const int lane = tid & 63, wv = tid >> 6, l31 = lane & 31, lh = lane >> 5;
    const int cbase = blockIdx.y * 1024 + wv * 256;

    float bestv[16]; int besti[16];
#pragma unroll
    for (int r = 0; r < 16; ++r) { bestv[r] = 3.0e38f; besti[r] = 0; }

#pragma unroll 1
    for (int ps = 0; ps < 2; ++ps) {         // 2 passes of 128 codes
        const int c0 = cbase + ps * 128;
        f32x16 acc[4];
#pragma unroll
        for (int tj = 0; tj < 4; ++tj)
#pragma unroll
            for (int i = 0; i < 16; ++i) acc[tj][i] = 0.0f;

#pragma unroll
        for (int ks = 0; ks < 16; ++ks) {
            const int Lg = ks * 2 + lh;
            f16x8 b0[4], b1[4];
#pragma unroll
            for (int tj = 0; tj < 4; ++tj) {
                const int c = c0 + tj * 32 + l31;
                const int eg = (c >> 8) * 8192 + Lg * 256 + (c & 255);
                b0[tj] = __builtin_bit_cast(f16x8, Eh[eg]);
                b1[tj] = __builtin_bit_cast(f16x8, El[eg]);
            }
            const f16x8 a0 = __builtin_bit_cast(f16x8, sAh[Lg * 32 + l31]);
            const f16x8 a1 = __builtin_bit_cast(f16x8, sAl[Lg * 32 + l31]);
#pragma unroll
            for (int tj = 0; tj < 4; ++tj) acc[tj] = MFMA32(a1, b0[tj], acc[tj]);
#pragma unroll
            for (int tj = 0; tj < 4; ++tj) acc[tj] = MFMA32(a0, b1[tj], acc[tj]);
#pragma unroll
            for (int tj = 0; tj < 4; ++tj) acc[tj] = MFMA32(a0, b0[tj], acc[tj]);
        }

#pragma unroll
        for (int tj = 0; tj < 4; ++tj) {
            const int c = c0 + tj * 32 + l31;
            const float eb = esqb[c];
#pragma unroll
            for (int r = 0; r < 16; ++r) {
                const float dv = fmaf(-2.0f, acc[tj][r], eb);
                if (dv < bestv[r]) { bestv[r] = dv; besti[r] = c; }
            }
        }
    }

#pragma unroll
    for (int r = 0; r < 16; ++r) {
        float v = bestv[r]; int bi = besti[r];
#pragma unroll
        for (int m = 16; m >= 1; m >>= 1) {
            const float ov = __shfl_xor(v, m, 32);
            const int   oi = __shfl_xor(bi, m, 32);
            if (ov < v || (ov == v && oi < bi)) { v = ov; bi = oi; }
        }
        if (l31 == 0) {
            const int rl = (r & 3) + 8 * (r >> 2) + 4 * lh;   // 0..31
            atomicMin(&res0[rows_s[rl]],
                      ((unsigned long long)__float_as_uint(v) << 32) | (unsigned)bi);
        }
    }
}

// ---------------------------------------------------------------------------
__global__ void finalize_kernel(const unsigned long long* __restrict__ res0,
                                const int* __restrict__ cnt, const int* __restrict__ list,
                                int* __restrict__ out) {
    const int i = blockIdx.x * 256 + threadIdx.x;
    if (i < *cnt) {
        const int row = list[i];
        out[row] = (int)(res0[row] & 0xFFFFFFFFull);
    }
}

// ---------------------------------------------------------------------------
// Fallback (round-4 verified): in-loop split, for small ws_size.
// ---------------------------------------------------------------------------
__global__ void prologue_fb(const float* __restrict__ E, float* __restrict__ esqb,
                            unsigned long long* __restrict__ packed) {
    const int t = blockIdx.x * 256 + threadIdx.x;
    if (t < N_ROWS) packed[t] = ~0ull;
    const int gw = t >> 6, lane = t & 63;
    const float4 v = ((const float4*)(E + (size_t)gw * D_DIM))[lane];
    float s = v.x * v.x + v.y * v.y + v.z * v.z + v.w * v.w;
#pragma unroll
    for (int off = 32; off; off >>= 1) s += __shfl_down(s, off, 64);
    if (lane == 0) esqb[gw] = s + 1024.0f;
}

__global__ __launch_bounds__(256, 2)
void vq_mfma_fallback(const float* __restrict__ X, const float* __restrict__ E,
                      const float* __restrict__ esqb,
                      unsigned long long* __restrict__ packed) {
    __shared__ uint4 fXh[128 * 8], fXl[128 * 8];
    __shared__ uint4 fEh[128 * 8], fEl[128 * 8];
    __shared__ float fEsq[2048];

    const int tid  = threadIdx.x;
    const int lane = tid & 63;
    const int wv   = tid >> 6;
    const int wr   = wv >> 1, wc = wv & 1;
    const int l31  = lane & 31;
    const int lh   = lane >> 5;
    const int row0 = blockIdx.x * 128;
    const int cs0  = blockIdx.y * 2048;

#pragma unroll
    for (int i = 0; i < 8; ++i) fEsq[tid + 256 * i] = esqb[cs0 + tid + 256 * i];

    const int sr = tid >> 3, sg = tid & 7;

    float best[2][16]; int bidx[2][16];
#pragma unroll
    for (int ti = 0; ti < 2; ++ti)
#pragma unroll
        for (int r = 0; r < 16; ++r) { best[ti][r] = 3.0e38f; bidx[ti][r] = 0; }

    f32x16 acc[2][2];

#pragma unroll 1
    for (int ct = 0; ct < 16; ++ct) {
#pragma unroll
        for (int ti = 0; ti < 2; ++ti)
#pragma unroll
            for (int tj = 0; tj < 2; ++tj)
#pragma unroll
                for (int i = 0; i < 16; ++i) acc[ti][tj][i] = 0.0f;

#pragma unroll 1
        for (int dc = 0; dc < 4; ++dc) {
            __syncthreads();
#pragma unroll
            for (int i = 0; i < 4; ++i) {
                const int r = 32 * i + sr;
                const float* p = X + (size_t)(row0 + r) * D_DIM + dc * 64 + sg * 8;
                const float4 a = *(const float4*)p, b = *(const float4*)(p + 4);
                uint4 hi, lo; cvt_granule(a, b, hi, lo);
                const int o = r * 8 + (sg ^ (r & 7));
                fXh[o] = hi; fXl[o] = lo;
            }
#pragma unroll
            for (int i = 0; i < 4; ++i) {
                const int r = 32 * i + sr;
                const float* p = E + (size_t)(cs0 + ct * 128 + r) * D_DIM + dc * 64 + sg * 8;
                const float4 a = *(const float4*)p, b = *(const float4*)(p + 4);
                uint4 hi, lo; cvt_granule(a, b, hi, lo);
                const int o = r * 8 + (sg ^ (r & 7));
                fEh[o] = hi; fEl[o] = lo;
            }
            __syncthreads();

#pragma unroll
            for (int s = 0; s < 4; ++s) {
                const int gi = s * 2 + lh;
                f16x8 axh[2], axl[2], beh[2], bel[2];
#pragma unroll
                for (int ti = 0; ti < 2; ++ti) {
                    const int r = wr * 64 + ti * 32 + l31;
                    const int o = r * 8 + (gi ^ (r & 7));
                    axh[ti] = __builtin_bit_cast(f16x8, fXh[o]);
                    axl[ti] = __builtin_bit_cast(f16x8, fXl[o]);
                }
#pragma unroll
                for (int tj = 0; tj < 2; ++tj) {
                    const int c = wc * 64 + tj * 32 + l31;
                    const int o = c * 8 + (gi ^ (c & 7));
                    beh[tj] = __builtin_bit_cast(f16x8, fEh[o]);
                    bel[tj] = __builtin_bit_cast(f16x8, fEl[o]);
                }
#pragma unroll
                for (int ti = 0; ti < 2; ++ti)
#pragma unroll
                    for (int tj = 0; tj < 2; ++tj) {
                        acc[ti][tj] = MFMA32(axl[ti], beh[tj], acc[ti][tj]);
                        acc[ti][tj] = MFMA32(axh[ti], bel[tj], acc[ti][tj]);
                        acc[ti][tj] = MFMA32(axh[ti], beh[tj], acc[ti][tj]);
                    }
            }
        }

#pragma unroll
        for (int tj = 0; tj < 2; ++tj) {
            const int cloc = ct * 128 + wc * 64 + tj * 32 + l31;
            const float eb = fEsq[cloc];
            const int  code = cs0 + cloc;
#pragma unroll
            for (int ti = 0; ti < 2; ++ti)
#pragma unroll
                for (int r = 0; r < 16; ++r) {
                    const float dv = fmaf(-2.0f, acc[ti][tj][r], eb);
                    if (dv < best[ti][r]) { best[ti][r] = dv; bidx[ti][r] = code; }
                }
        }
    }

#pragma unroll
    for (int ti = 0; ti < 2; ++ti)
#pragma unroll
        for (int r = 0; r < 16; ++r) {
            float b = best[ti][r]; int bi = bidx[ti][r];
#pragma unroll
            for (int m = 16; m >= 1; m >>= 1) {
                const float ov = __shfl_xor(b, m, 32);
                const int   oi = __shfl_xor(bi, m, 32);
                if (ov < b || (ov == b && oi < bi)) { b = ov; bi = oi; }
            }
            if (l31 == 0) {
                const int row = row0 + wr * 64 + ti * 32 + (r & 3) + 8 * (r >> 2) + 4 * lh;
                const unsigned long long p =
                    ((unsigned long long)__float_as_uint(b) << 32) | (unsigned)bi;
                atomicMin(&packed[row], p);
            }
        }
}

__global__ void finish_fb(const unsigned long long* __restrict__ packed,
                          int* __restrict__ out) {
    const int i = blockIdx.x * 256 + threadIdx.x;
    out[i] = (int)(unsigned)(packed[i] & 0xffffffffull);
}

// ---------------------------------------------------------------------------
extern "C" void kernel_launch(void* const* d_in, const int* in_sizes, int n_in,
                              void* d_out, int out_size, void* d_ws, size_t ws_size,
                              hipStream_t stream) {
    const float* X = (const float*)d_in[0];    // [32768, 256]
    const float* E = (const float*)d_in[1];    // [8192, 256]
    char* ws = (char*)d_ws;
    int* out = (int*)d_out;

    float* esqb = (float*)ws;                                    // 32 KB @ 0
    uint2* res  = (uint2*)(ws + 32768);                          // 1 MB (4 strips)
    unsigned long long* res0 = (unsigned long long*)(ws + 1081344); // 256 KB
    int* cnt  = (int*)(ws + 1343488);                            // 16 B
    int* list = (int*)(ws + 1343504);                            // 128 KB
    const size_t base = 1572864;                                 // 1.5 MB
    const size_t szX  = (size_t)N_ROWS * D_DIM * 2;              // 16 MB (hi only)
    const size_t szE  = (size_t)K_CODES * D_DIM * 2;             // 4 MB per half
    const size_t need = base + szX + 2 * szE;                    // ~25.5 MB

    if (ws_size >= need) {
        uint4* Xh = (uint4*)(ws + base);
        uint4* Eh = (uint4*)(ws + base + szX);
        uint4* El = (uint4*)(ws + base + szX + szE);
        prep_kernel<<<dim3(3328), dim3(256), 0, stream>>>(X, E, Xh, Eh, El, esqb, cnt);
        vq_pass1<<<dim3(2048), dim3(256), 0, stream>>>(Xh, Eh, esqb, res);
        merge_kernel<<<dim3(N_ROWS / 256), dim3(256), 0, stream>>>(res, res0, out, cnt, list);
        refine_kernel<<<dim3(1024, 8), dim3(256), 0, stream>>>(X, Eh, El, esqb,
                                                               cnt, list, res0);
        finalize_kernel<<<dim3(N_ROWS / 256), dim3(256), 0, stream>>>(res0, cnt, list, out);
    } else {
        unsigned long long* packed = (unsigned long long*)(ws + 32768);
        prologue_fb<<<dim3(2048), dim3(256), 0, stream>>>(E, esqb, packed);
        vq_mfma_fallback<<<dim3(N_ROWS / 128, 4), dim3(256), 0, stream>>>(X, E, esqb, packed);
        finish_fb<<<dim3(N_ROWS / 256), dim3(256), 0, stream>>>(packed, out);
    }
}

// Round 6
// 324.565 us; speedup vs baseline: 1.6065x; 1.0125x over previous
//
#include <hip/hip_runtime.h>

// N=32768 rows, K=8192 codes, D=256, fp32 in, int32 out.
constexpr int D_DIM   = 256;
constexpr int N_ROWS  = 32768;
constexpr int K_CODES = 8192;
// Quantized screen: dist*128 in key high bits. TQ/128 = 0.453 effective tau
// (round-10 verified tau=0.45 class; covers split error ~0.3 + quant 0.016).
constexpr unsigned TQ = 58;

typedef _Float16 f16x8  __attribute__((ext_vector_type(8)));
typedef __fp16   fp16x2 __attribute__((ext_vector_type(2)));
typedef float    f32x16 __attribute__((ext_vector_type(16)));

#define MFMA32(a, b, c) __builtin_amdgcn_mfma_f32_32x32x16_f16(a, b, c, 0, 0, 0)

// RTN split: hi = rn16(x), lo = rn16(x - hi).
__device__ __forceinline__ void cvt_rtn(const float4 a, const float4 b,
                                        uint4& hi, uint4& lo) {
    float f[8] = {a.x, a.y, a.z, a.w, b.x, b.y, b.z, b.w};
    unsigned hb[8], lb[8];
#pragma unroll
    for (int i = 0; i < 8; ++i) {
        _Float16 h = (_Float16)f[i];
        _Float16 l = (_Float16)(f[i] - (float)h);
        hb[i] = __builtin_bit_cast(unsigned short, h);
        lb[i] = __builtin_bit_cast(unsigned short, l);
    }
    hi = make_uint4(hb[0] | (hb[1] << 16), hb[2] | (hb[3] << 16),
                    hb[4] | (hb[5] << 16), hb[6] | (hb[7] << 16));
    lo = make_uint4(lb[0] | (lb[1] << 16), lb[2] | (lb[3] << 16),
                    lb[4] | (lb[5] << 16), lb[6] | (lb[7] << 16));
}

// RTZ split used by the (verified) fallback path.
__device__ __forceinline__ void cvt_granule(const float4 a, const float4 b,
                                            uint4& hi, uint4& lo) {
    fp16x2 h0 = __builtin_amdgcn_cvt_pkrtz(a.x, a.y);
    fp16x2 h1 = __builtin_amdgcn_cvt_pkrtz(a.z, a.w);
    fp16x2 h2 = __builtin_amdgcn_cvt_pkrtz(b.x, b.y);
    fp16x2 h3 = __builtin_amdgcn_cvt_pkrtz(b.z, b.w);
    fp16x2 l0 = __builtin_amdgcn_cvt_pkrtz(a.x - (float)h0.x, a.y - (float)h0.y);
    fp16x2 l1 = __builtin_amdgcn_cvt_pkrtz(a.z - (float)h1.x, a.w - (float)h1.y);
    fp16x2 l2 = __builtin_amdgcn_cvt_pkrtz(b.x - (float)h2.x, b.y - (float)h2.y);
    fp16x2 l3 = __builtin_amdgcn_cvt_pkrtz(b.z - (float)h3.x, b.w - (float)h3.y);
    hi = make_uint4(__builtin_bit_cast(unsigned, h0), __builtin_bit_cast(unsigned, h1),
                    __builtin_bit_cast(unsigned, h2), __builtin_bit_cast(unsigned, h3));
    lo = make_uint4(__builtin_bit_cast(unsigned, l0), __builtin_bit_cast(unsigned, l1),
                    __builtin_bit_cast(unsigned, l2), __builtin_bit_cast(unsigned, l3));
}

__device__ __forceinline__ void gl_lds16(const uint4* g, uint4* l) {
    __builtin_amdgcn_global_load_lds(
        (const __attribute__((address_space(1))) void*)g,
        (__attribute__((address_space(3))) void*)l, 16, 0, 0);
}

// ---------------------------------------------------------------------------
// Prep: RTN hi split of X, hi/lo split of E, esqb, counter zero.
//  X: g = rb*2048 + Lg*64 + r    (rb: 64-row block, Lg = d/8 layer 0..31)
//  E: g = cb*8192 + Lg*256 + c   (cb: 256-code tile)
// ---------------------------------------------------------------------------
__global__ __launch_bounds__(256)
void prep_kernel(const float* __restrict__ X, const float* __restrict__ E,
                 uint4* __restrict__ Xh,
                 uint4* __restrict__ Eh, uint4* __restrict__ El,
                 float* __restrict__ esqb, int* __restrict__ cnt) {
    const int tid = threadIdx.x, bid = blockIdx.x;
    if (bid < 1024) {
#pragma unroll 1
        for (int it = 0; it < 4; ++it) {
            const int gid = bid * 1024 + it * 256 + tid;
            const int rb = gid >> 11, rem = gid & 2047;
            const int Lg = rem >> 6, r = rem & 63;
            const float* p = X + (size_t)(rb * 64 + r) * D_DIM + Lg * 8;
            const float4 a = *(const float4*)p, b = *(const float4*)(p + 4);
            uint4 hi, lo; cvt_rtn(a, b, hi, lo);
            Xh[gid] = hi;
        }
    } else if (bid < 1280) {
#pragma unroll 1
        for (int it = 0; it < 4; ++it) {
            const int gid = (bid - 1024) * 1024 + it * 256 + tid;
            const int cb = gid >> 13, rem = gid & 8191;
            const int Lg = rem >> 8, c = rem & 255;
            const float* p = E + (size_t)(cb * 256 + c) * D_DIM + Lg * 8;
            const float4 a = *(const float4*)p, b = *(const float4*)(p + 4);
            uint4 hi, lo; cvt_rtn(a, b, hi, lo);
            Eh[gid] = hi; El[gid] = lo;
        }
    } else {
        if (bid == 1280 && tid == 0) *cnt = 0;
        const int t = (bid - 1280) * 256 + tid;
        const int gw = t >> 6, lane = t & 63;
        const float4 v = ((const float4*)(E + (size_t)gw * D_DIM))[lane];
        float s = v.x * v.x + v.y * v.y + v.z * v.z + v.w * v.w;
#pragma unroll
        for (int off = 32; off; off >>= 1) s += __shfl_down(s, off, 64);
        if (lane == 0) esqb[gw] = s + 1024.0f;
    }
}

// ---------------------------------------------------------------------------
// Pass 1: 1-product (xh*eh) screen, quantized-key top-2 (pure u32 lattice).
// 64-row X block (32 KB hi) staged to LDS ONCE; wave tile 64 rows x 64 codes.
// Latency fix (R1-R5 lesson): per HALF-TILE (8 k-steps) all 16 E granules are
// loaded into a statically-indexed b[16] batch (64 VGPR, live only within the
// body -- no cross-iteration rotation / conditional copies, which spilled in
// R3/R4), then 32 straight-line MFMAs (~1033 SIMD-cy) consume them under
// counted vmcnt. launch_bounds(256,2): 2 blocks/CU -- the other wave on the
// SIMD covers the one ~300cy boundary stall per half-tile. setprio(1) wraps
// the MFMA cluster (waves alternate load/MFMA roles -> arbitrage pays).
// True VALU (lattice) is only ~3-4% of time (VALUBusy counter includes MFMA
// issue on gfx94x-fallback formulas) -- the stall was all load latency.
// ---------------------------------------------------------------------------
__global__ __launch_bounds__(256, 2)
void vq_pass1(const uint4* __restrict__ Xh, const uint4* __restrict__ Eh,
              const float* __restrict__ esqb, uint2* __restrict__ res) {
    __shared__ uint4 sXh[2048];      // [Lg(32)][r(64)], 32 KB
    __shared__ uint2 slot[4][64];    // [wave][row], 2 KB

    const int tid  = threadIdx.x;
    const int lane = tid & 63, wv = tid >> 6;
    const int l31  = lane & 31, lh = lane >> 5;
    const int bid  = blockIdx.x;
    const int bx = bid & 511, strip = bid >> 9;   // strip-chunked: co-resident
    const int cs0 = strip * 2048;                 // blocks share one E strip

    const uint4* Xhb = Xh + bx * 2048;

    // ---- stage X hi (whole 256-d, 64 rows) once ----
#pragma unroll
    for (int i = 0; i < 8; ++i)
        gl_lds16(Xhb + i * 256 + tid, &sXh[i * 256 + (wv << 6)]);
    __syncthreads();

    unsigned best[2][16], best2[2][16];
#pragma unroll
    for (int ti = 0; ti < 2; ++ti)
#pragma unroll
        for (int r = 0; r < 16; ++r) { best[ti][r] = 0xFFFFFFFFu; best2[ti][r] = 0xFFFFFFFFu; }

    f32x16 acc[2][2];

#pragma unroll 1
    for (int ct = 0; ct < 8; ++ct) {        // 256-code tiles
        // E base for this wave's 64-code column (lane-contiguous granules)
        const uint4* __restrict__ Eb =
            Eh + (size_t)(strip * 8 + ct) * 8192 + wv * 64 + l31;

        // hoist epilogue operands: no VMEM wait at epilogue start
        const int code0 = cs0 + ct * 256 + wv * 64 + l31;
        const float eb0 = esqb[code0] * 128.0f;        // (e_sq+1024)*128
        const float eb1 = esqb[code0 + 32] * 128.0f;

#pragma unroll
        for (int ti = 0; ti < 2; ++ti)
#pragma unroll
            for (int tj = 0; tj < 2; ++tj)
#pragma unroll
                for (int i = 0; i < 16; ++i) acc[ti][tj][i] = 0.0f;

#pragma unroll 1
        for (int h = 0; h < 2; ++h) {        // half-tiles of 8 k-steps
            const int kb = h * 8;
            // batch-issue all 16 E-granule loads of this half-tile
            f16x8 b[16];
#pragma unroll
            for (int j = 0; j < 8; ++j) {
                const int Lg = (kb + j) * 2 + lh;
                b[j * 2]     = __builtin_bit_cast(f16x8, Eb[Lg * 256]);
                b[j * 2 + 1] = __builtin_bit_cast(f16x8, Eb[Lg * 256 + 32]);
            }
            // 32 straight-line MFMAs drain the batch under counted vmcnt
            __builtin_amdgcn_s_setprio(1);
#pragma unroll
            for (int k = 0; k < 8; ++k) {
                const int Lg = (kb + k) * 2 + lh;
                const f16x8 a0 = __builtin_bit_cast(f16x8, sXh[Lg * 64 + l31]);
                const f16x8 a1 = __builtin_bit_cast(f16x8, sXh[Lg * 64 + l31 + 32]);
                acc[0][0] = MFMA32(a0, b[k * 2],     acc[0][0]);
                acc[0][1] = MFMA32(a0, b[k * 2 + 1], acc[0][1]);
                acc[1][0] = MFMA32(a1, b[k * 2],     acc[1][0]);
                acc[1][1] = MFMA32(a1, b[k * 2 + 1], acc[1][1]);
            }
            __builtin_amdgcn_s_setprio(0);
        }

        // epilogue: keyed top-2 lattice update (order-free)
#pragma unroll
        for (int tj = 0; tj < 2; ++tj) {
            const unsigned code = (unsigned)(code0 + tj * 32);
            const float eb128 = tj ? eb1 : eb0;
#pragma unroll
            for (int ti = 0; ti < 2; ++ti)
#pragma unroll
                for (int r = 0; r < 16; ++r) {
                    const float dq = fmaf(-256.0f, acc[ti][tj][r], eb128);
                    const unsigned q   = (unsigned)dq;          // < 2^19
                    const unsigned key = (q << 13) + code;
                    // invariant best<=best2: new best2 = median(key,best,best2)
                    unsigned nb2;
                    asm("v_med3_u32 %0, %1, %2, %3"
                        : "=v"(nb2)
                        : "v"(key), "v"(best[ti][r]), "v"(best2[ti][r]));
                    best2[ti][r] = nb2;
                    best[ti][r]  = key < best[ti][r] ? key : best[ti][r];
                }
        }
    }

    // butterfly over 32 code-lanes (exact top-2 merge, u32)
#pragma unroll
    for (int ti = 0; ti < 2; ++ti)
#pragma unroll
        for (int r = 0; r < 16; ++r) {
            unsigned b1 = best[ti][r], b2 = best2[ti][r];
#pragma unroll
            for (int m = 16; m >= 1; m >>= 1) {
                const unsigned o1 = (unsigned)__shfl_xor((int)b1, m, 32);
                const unsigned o2 = (unsigned)__shfl_xor((int)b2, m, 32);
                const unsigned t  = b1 > o1 ? b1 : o1;
                b1 = b1 < o1 ? b1 : o1;
                const unsigned m2 = b2 < o2 ? b2 : o2;
                b2 = m2 < t ? m2 : t;
            }
            if (l31 == 0) {
                const int row = ti * 32 + (r & 3) + 8 * (r >> 2) + 4 * lh;
                slot[wv][row] = make_uint2(b1, b2);
            }
        }

    __syncthreads();
    if (tid < 64) {
        const uint2 A = slot[0][tid];
        unsigned b1 = A.x, b2 = A.y;
#pragma unroll
        for (int s = 1; s < 4; ++s) {
            const uint2 B = slot[s][tid];
            const unsigned t  = b1 > B.x ? b1 : B.x;
            b1 = b1 < B.x ? b1 : B.x;
            const unsigned m2 = b2 < B.y ? b2 : B.y;
            b2 = m2 < t ? m2 : t;
        }
        res[(size_t)strip * N_ROWS + bx * 64 + tid] = make_uint2(b1, b2);
    }
}

// ---------------------------------------------------------------------------
// Merge 4 strips (exact keyed top-2): clean rows -> out; ambiguous -> list.
// ---------------------------------------------------------------------------
__global__ void merge_kernel(const uint2* __restrict__ res,
                             unsigned long long* __restrict__ res0,
                             int* __restrict__ out,
                             int* __restrict__ cnt, int* __restrict__ list) {
    const int row = blockIdx.x * 256 + threadIdx.x;
    unsigned b1 = 0xFFFFFFFFu, b2 = 0xFFFFFFFFu;
#pragma unroll
    for (int s = 0; s < 4; ++s) {
        const uint2 v = res[(size_t)s * N_ROWS + row];
        const unsigned t = b1 > v.x ? b1 : v.x;
        b1 = b1 < v.x ? b1 : v.x;
        const unsigned m2 = b2 < v.y ? b2 : v.y;
        b2 = m2 < t ? m2 : t;
    }
    out[row] = (int)(b1 & 8191u);
    if ((b2 >> 13) - (b1 >> 13) < TQ) {
        const int p = atomicAdd(cnt, 1);
        list[p] = row;
        res0[row] = ~0ull;
    }
}

// ---------------------------------------------------------------------------
// Refine: flagged rows, exact 3-product over all codes (verified structure).
// Block = 32 gathered rows x 1024-code strip (grid 1024 x 8, uniform exit).
// A rows converted from raw fp32 on the fly (same RTN split as prep).
// ---------------------------------------------------------------------------
__global__ __launch_bounds__(256, 1)
void refine_kernel(const float* __restrict__ X,
                   const uint4* __restrict__ Eh, const uint4* __restrict__ El,
                   const float* __restrict__ esqb, const int* __restrict__ cnt,
                   const int* __restrict__ list, unsigned long long* __restrict__ res0) {
    __shared__ int  rows_s[32];
    __shared__ uint4 sAh[1024], sAl[1024];   // 32 KB

    const int n = *cnt;
    const int base = blockIdx.x * 32;
    if (base >= n) return;                   // block-uniform
    const int tid = threadIdx.x;
    if (tid < 32) { const int j = base + tid; rows_s[tid] = list[j < n ? j : base]; }
    __syncthreads();

    // gather + split A: granule slot Lg (0..31) x row slot rr (0..31)
#pragma unroll
    for (int jj = 0; jj < 4; ++jj) {
        const int gg = jj * 256 + tid, Lg = gg >> 5, rr = gg & 31;
        const int row = rows_s[rr];
        const float* p = X + (size_t)row * D_DIM + Lg * 8;
        const float4 a = *(const float4*)p, b = *(const float4*)(p + 4);
        uint4 hi, lo; cvt_rtn(a, b, hi, lo);
        sAh[Lg * 32 + rr] = hi; sAl[Lg * 32 + rr] = lo;
    }
    __syncthreads();

    const int lane = tid & 63, wv = tid >> 6, l31 = lane & 31, lh = lane >> 5;
    const int cbase = blockIdx.y * 1024 + wv * 256;

    float bestv[16]; int besti[16];
#pragma unroll
    for (int r = 0; r < 16; ++r) { bestv[r] = 3.0e38f; besti[r] = 0; }

#pragma unroll 1
    for (int ps = 0; ps < 2; ++ps) {         // 2 passes of 128 codes
        const int c0 = cbase + ps * 128;
        f32x16 acc[4];
#pragma unroll
        for (int tj = 0; tj < 4; ++tj)
#pragma unroll
            for (int i = 0; i < 16; ++i) acc[tj][i] = 0.0f;

#pragma unroll
        for (int ks = 0; ks < 16; ++ks) {
            const int Lg = ks * 2 + lh;
            f16x8 b0[4], b1[4];
#pragma unroll
            for (int tj = 0; tj < 4; ++tj) {
                const int c = c0 + tj * 32 + l31;
                const int eg = (c >> 8) * 8192 + Lg * 256 + (c & 255);
                b0[tj] = __builtin_bit_cast(f16x8, Eh[eg]);
                b1[tj] = __builtin_bit_cast(f16x8, El[eg]);
            }
            const f16x8 a0 = __builtin_bit_cast(f16x8, sAh[Lg * 32 + l31]);
            const f16x8 a1 = __builtin_bit_cast(f16x8, sAl[Lg * 32 + l31]);
#pragma unroll
            for (int tj = 0; tj < 4; ++tj) acc[tj] = MFMA32(a1, b0[tj], acc[tj]);
#pragma unroll
            for (int tj = 0; tj < 4; ++tj) acc[tj] = MFMA32(a0, b1[tj], acc[tj]);
#pragma unroll
            for (int tj = 0; tj < 4; ++tj) acc[tj] = MFMA32(a0, b0[tj], acc[tj]);
        }

#pragma unroll
        for (int tj = 0; tj < 4; ++tj) {
            const int c = c0 + tj * 32 + l31;
            const float eb = esqb[c];
#pragma unroll
            for (int r = 0; r < 16; ++r) {
                const float dv = fmaf(-2.0f, acc[tj][r], eb);
                if (dv < bestv[r]) { bestv[r] = dv; besti[r] = c; }
            }
        }
    }

#pragma unroll
    for (int r = 0; r < 16; ++r) {
        float v = bestv[r]; int bi = besti[r];
#pragma unroll
        for (int m = 16; m >= 1; m >>= 1) {
            const float ov = __shfl_xor(v, m, 32);
            const int   oi = __shfl_xor(bi, m, 32);
            if (ov < v || (ov == v && oi < bi)) { v = ov; bi = oi; }
        }
        if (l31 == 0) {
            const int rl = (r & 3) + 8 * (r >> 2) + 4 * lh;   // 0..31
            atomicMin(&res0[rows_s[rl]],
                      ((unsigned long long)__float_as_uint(v) << 32) | (unsigned)bi);
        }
    }
}

// ---------------------------------------------------------------------------
__global__ void finalize_kernel(const unsigned long long* __restrict__ res0,
                                const int* __restrict__ cnt, const int* __restrict__ list,
                                int* __restrict__ out) {
    const int i = blockIdx.x * 256 + threadIdx.x;
    if (i < *cnt) {
        const int row = list[i];
        out[row] = (int)(res0[row] & 0xFFFFFFFFull);
    }
}

// ---------------------------------------------------------------------------
// Fallback (round-4 verified): in-loop split, for small ws_size.
// ---------------------------------------------------------------------------
__global__ void prologue_fb(const float* __restrict__ E, float* __restrict__ esqb,
                            unsigned long long* __restrict__ packed) {
    const int t = blockIdx.x * 256 + threadIdx.x;
    if (t < N_ROWS) packed[t] = ~0ull;
    const int gw = t >> 6, lane = t & 63;
    const float4 v = ((const float4*)(E + (size_t)gw * D_DIM))[lane];
    float s = v.x * v.x + v.y * v.y + v.z * v.z + v.w * v.w;
#pragma unroll
    for (int off = 32; off; off >>= 1) s += __shfl_down(s, off, 64);
    if (lane == 0) esqb[gw] = s + 1024.0f;
}

__global__ __launch_bounds__(256, 2)
void vq_mfma_fallback(const float* __restrict__ X, const float* __restrict__ E,
                      const float* __restrict__ esqb,
                      unsigned long long* __restrict__ packed) {
    __shared__ uint4 fXh[128 * 8], fXl[128 * 8];
    __shared__ uint4 fEh[128 * 8], fEl[128 * 8];
    __shared__ float fEsq[2048];

    const int tid  = threadIdx.x;
    const int lane = tid & 63;
    const int wv   = tid >> 6;
    const int wr   = wv >> 1, wc = wv & 1;
    const int l31  = lane & 31;
    const int lh   = lane >> 5;
    const int row0 = blockIdx.x * 128;
    const int cs0  = blockIdx.y * 2048;

#pragma unroll
    for (int i = 0; i < 8; ++i) fEsq[tid + 256 * i] = esqb[cs0 + tid + 256 * i];

    const int sr = tid >> 3, sg = tid & 7;

    float best[2][16]; int bidx[2][16];
#pragma unroll
    for (int ti = 0; ti < 2; ++ti)
#pragma unroll
        for (int r = 0; r < 16; ++r) { best[ti][r] = 3.0e38f; bidx[ti][r] = 0; }

    f32x16 acc[2][2];

#pragma unroll 1
    for (int ct = 0; ct < 16; ++ct) {
#pragma unroll
        for (int ti = 0; ti < 2; ++ti)
#pragma unroll
            for (int tj = 0; tj < 2; ++tj)
#pragma unroll
                for (int i = 0; i < 16; ++i) acc[ti][tj][i] = 0.0f;

#pragma unroll 1
        for (int dc = 0; dc < 4; ++dc) {
            __syncthreads();
#pragma unroll
            for (int i = 0; i < 4; ++i) {
                const int r = 32 * i + sr;
                const float* p = X + (size_t)(row0 + r) * D_DIM + dc * 64 + sg * 8;
                const float4 a = *(const float4*)p, b = *(const float4*)(p + 4);
                uint4 hi, lo; cvt_granule(a, b, hi, lo);
                const int o = r * 8 + (sg ^ (r & 7));
                fXh[o] = hi; fXl[o] = lo;
            }
#pragma unroll
            for (int i = 0; i < 4; ++i) {
                const int r = 32 * i + sr;
                const float* p = E + (size_t)(cs0 + ct * 128 + r) * D_DIM + dc * 64 + sg * 8;
                const float4 a = *(const float4*)p, b = *(const float4*)(p + 4);
                uint4 hi, lo; cvt_granule(a, b, hi, lo);
                const int o = r * 8 + (sg ^ (r & 7));
                fEh[o] = hi; fEl[o] = lo;
            }
            __syncthreads();

#pragma unroll
            for (int s = 0; s < 4; ++s) {
                const int gi = s * 2 + lh;
                f16x8 axh[2], axl[2], beh[2], bel[2];
#pragma unroll
                for (int ti = 0; ti < 2; ++ti) {
                    const int r = wr * 64 + ti * 32 + l31;
                    const int o = r * 8 + (gi ^ (r & 7));
                    axh[ti] = __builtin_bit_cast(f16x8, fXh[o]);
                    axl[ti] = __builtin_bit_cast(f16x8, fXl[o]);
                }
#pragma unroll
                for (int tj = 0; tj < 2; ++tj) {
                    const int c = wc * 64 + tj * 32 + l31;
                    const int o = c * 8 + (gi ^ (c & 7));
                    beh[tj] = __builtin_bit_cast(f16x8, fEh[o]);
                    bel[tj] = __builtin_bit_cast(f16x8, fEl[o]);
                }
#pragma unroll
                for (int ti = 0; ti < 2; ++ti)
#pragma unroll
                    for (int tj = 0; tj < 2; ++tj) {
                        acc[ti][tj] = MFMA32(axl[ti], beh[tj], acc[ti][tj]);
                        acc[ti][tj] = MFMA32(axh[ti], bel[tj], acc[ti][tj]);
                        acc[ti][tj] = MFMA32(axh[ti], beh[tj], acc[ti][tj]);
                    }
            }
        }

#pragma unroll
        for (int tj = 0; tj < 2; ++tj) {
            const int cloc = ct * 128 + wc * 64 + tj * 32 + l31;
            const float eb = fEsq[cloc];
            const int  code = cs0 + cloc;
#pragma unroll
            for (int ti = 0; ti < 2; ++ti)
#pragma unroll
                for (int r = 0; r < 16; ++r) {
                    const float dv = fmaf(-2.0f, acc[ti][tj][r], eb);
                    if (dv < best[ti][r]) { best[ti][r] = dv; bidx[ti][r] = code; }
                }
        }
    }

#pragma unroll
    for (int ti = 0; ti < 2; ++ti)
#pragma unroll
        for (int r = 0; r < 16; ++r) {
            float b = best[ti][r]; int bi = bidx[ti][r];
#pragma unroll
            for (int m = 16; m >= 1; m >>= 1) {
                const float ov = __shfl_xor(b, m, 32);
                const int   oi = __shfl_xor(bi, m, 32);
                if (ov < b || (ov == b && oi < bi)) { b = ov; bi = oi; }
            }
            if (l31 == 0) {
                const int row = row0 + wr * 64 + ti * 32 + (r & 3) + 8 * (r >> 2) + 4 * lh;
                const unsigned long long p =
                    ((unsigned long long)__float_as_uint(b) << 32) | (unsigned)bi;
                atomicMin(&packed[row], p);
            }
        }
}

__global__ void finish_fb(const unsigned long long* __restrict__ packed,
                          int* __restrict__ out) {
    const int i = blockIdx.x * 256 + threadIdx.x;
    out[i] = (int)(unsigned)(packed[i] & 0xffffffffull);
}

// ---------------------------------------------------------------------------
extern "C" void kernel_launch(void* const* d_in, const int* in_sizes, int n_in,
                              void* d_out, int out_size, void* d_ws, size_t ws_size,
                              hipStream_t stream) {
    const float* X = (const float*)d_in[0];    // [32768, 256]
    const float* E = (const float*)d_in[1];    // [8192, 256]
    char* ws = (char*)d_ws;
    int* out = (int*)d_out;

    float* esqb = (float*)ws;                                    // 32 KB @ 0
    uint2* res  = (uint2*)(ws + 32768);                          // 1 MB (4 strips)
    unsigned long long* res0 = (unsigned long long*)(ws + 1081344); // 256 KB
    int* cnt  = (int*)(ws + 1343488);                            // 16 B
    int* list = (int*)(ws + 1343504);                            // 128 KB
    const size_t base = 1572864;                                 // 1.5 MB
    const size_t szX  = (size_t)N_ROWS * D_DIM * 2;              // 16 MB (hi only)
    const size_t szE  = (size_t)K_CODES * D_DIM * 2;             // 4 MB per half
    const size_t need = base + szX + 2 * szE;                    // ~25.5 MB

    if (ws_size >= need) {
        uint4* Xh = (uint4*)(ws + base);
        uint4* Eh = (uint4*)(ws + base + szX);
        uint4* El = (uint4*)(ws + base + szX + szE);
        prep_kernel<<<dim3(3328), dim3(256), 0, stream>>>(X, E, Xh, Eh, El, esqb, cnt);
        vq_pass1<<<dim3(2048), dim3(256), 0, stream>>>(Xh, Eh, esqb, res);
        merge_kernel<<<dim3(N_ROWS / 256), dim3(256), 0, stream>>>(res, res0, out, cnt, list);
        refine_kernel<<<dim3(1024, 8), dim3(256), 0, stream>>>(X, Eh, El, esqb,
                                                               cnt, list, res0);
        finalize_kernel<<<dim3(N_ROWS / 256), dim3(256), 0, stream>>>(res0, cnt, list, out);
    } else {
        unsigned long long* packed = (unsigned long long*)(ws + 32768);
        prologue_fb<<<dim3(2048), dim3(256), 0, stream>>>(E, esqb, packed);
        vq_mfma_fallback<<<dim3(N_ROWS / 128, 4), dim3(256), 0, stream>>>(X, E, esqb, packed);
        finish_fb<<<dim3(N_ROWS / 256), dim3(256), 0, stream>>>(packed, out);
    }
}

// Round 7
// 307.704 us; speedup vs baseline: 1.6946x; 1.0548x over previous
//
#include <hip/hip_runtime.h>

// N=32768 rows, K=8192 codes, D=256, fp32 in, int32 out.
constexpr int D_DIM   = 256;
constexpr int N_ROWS  = 32768;
constexpr int K_CODES = 8192;
// Quantized screen: dist*128 in key high bits. TQ/128 = 0.453 effective tau
// (round-10 verified tau=0.45 class; covers split error ~0.3 + quant 0.016).
constexpr unsigned TQ = 58;

typedef _Float16 f16x8  __attribute__((ext_vector_type(8)));
typedef __fp16   fp16x2 __attribute__((ext_vector_type(2)));
typedef float    f32x16 __attribute__((ext_vector_type(16)));

#define MFMA32(a, b, c) __builtin_amdgcn_mfma_f32_32x32x16_f16(a, b, c, 0, 0, 0)

// RTN split: hi = rn16(x), lo = rn16(x - hi).
__device__ __forceinline__ void cvt_rtn(const float4 a, const float4 b,
                                        uint4& hi, uint4& lo) {
    float f[8] = {a.x, a.y, a.z, a.w, b.x, b.y, b.z, b.w};
    unsigned hb[8], lb[8];
#pragma unroll
    for (int i = 0; i < 8; ++i) {
        _Float16 h = (_Float16)f[i];
        _Float16 l = (_Float16)(f[i] - (float)h);
        hb[i] = __builtin_bit_cast(unsigned short, h);
        lb[i] = __builtin_bit_cast(unsigned short, l);
    }
    hi = make_uint4(hb[0] | (hb[1] << 16), hb[2] | (hb[3] << 16),
                    hb[4] | (hb[5] << 16), hb[6] | (hb[7] << 16));
    lo = make_uint4(lb[0] | (lb[1] << 16), lb[2] | (lb[3] << 16),
                    lb[4] | (lb[5] << 16), lb[6] | (lb[7] << 16));
}

// RTZ split used by the (verified) fallback path.
__device__ __forceinline__ void cvt_granule(const float4 a, const float4 b,
                                            uint4& hi, uint4& lo) {
    fp16x2 h0 = __builtin_amdgcn_cvt_pkrtz(a.x, a.y);
    fp16x2 h1 = __builtin_amdgcn_cvt_pkrtz(a.z, a.w);
    fp16x2 h2 = __builtin_amdgcn_cvt_pkrtz(b.x, b.y);
    fp16x2 h3 = __builtin_amdgcn_cvt_pkrtz(b.z, b.w);
    fp16x2 l0 = __builtin_amdgcn_cvt_pkrtz(a.x - (float)h0.x, a.y - (float)h0.y);
    fp16x2 l1 = __builtin_amdgcn_cvt_pkrtz(a.z - (float)h1.x, a.w - (float)h1.y);
    fp16x2 l2 = __builtin_amdgcn_cvt_pkrtz(b.x - (float)h2.x, b.y - (float)h2.y);
    fp16x2 l3 = __builtin_amdgcn_cvt_pkrtz(b.z - (float)h3.x, b.w - (float)h3.y);
    hi = make_uint4(__builtin_bit_cast(unsigned, h0), __builtin_bit_cast(unsigned, h1),
                    __builtin_bit_cast(unsigned, h2), __builtin_bit_cast(unsigned, h3));
    lo = make_uint4(__builtin_bit_cast(unsigned, l0), __builtin_bit_cast(unsigned, l1),
                    __builtin_bit_cast(unsigned, l2), __builtin_bit_cast(unsigned, l3));
}

__device__ __forceinline__ void gl_lds16(const uint4* g, uint4* l) {
    __builtin_amdgcn_global_load_lds(
        (const __attribute__((address_space(1))) void*)g,
        (__attribute__((address_space(3))) void*)l, 16, 0, 0);
}

// ---------------------------------------------------------------------------
// Prep: RTN hi split of X, hi/lo split of E, esqb, counter zero.
//  X: g = rb*2048 + Lg*64 + r    (rb: 64-row block, Lg = d/8 layer 0..31)
//  E: g = cb*8192 + Lg*256 + c   (cb: 256-code tile)
// ---------------------------------------------------------------------------
__global__ __launch_bounds__(256)
void prep_kernel(const float* __restrict__ X, const float* __restrict__ E,
                 uint4* __restrict__ Xh,
                 uint4* __restrict__ Eh, uint4* __restrict__ El,
                 float* __restrict__ esqb, int* __restrict__ cnt) {
    const int tid = threadIdx.x, bid = blockIdx.x;
    if (bid < 1024) {
#pragma unroll 1
        for (int it = 0; it < 4; ++it) {
            const int gid = bid * 1024 + it * 256 + tid;
            const int rb = gid >> 11, rem = gid & 2047;
            const int Lg = rem >> 6, r = rem & 63;
            const float* p = X + (size_t)(rb * 64 + r) * D_DIM + Lg * 8;
            const float4 a = *(const float4*)p, b = *(const float4*)(p + 4);
            uint4 hi, lo; cvt_rtn(a, b, hi, lo);
            Xh[gid] = hi;
        }
    } else if (bid < 1280) {
#pragma unroll 1
        for (int it = 0; it < 4; ++it) {
            const int gid = (bid - 1024) * 1024 + it * 256 + tid;
            const int cb = gid >> 13, rem = gid & 8191;
            const int Lg = rem >> 8, c = rem & 255;
            const float* p = E + (size_t)(cb * 256 + c) * D_DIM + Lg * 8;
            const float4 a = *(const float4*)p, b = *(const float4*)(p + 4);
            uint4 hi, lo; cvt_rtn(a, b, hi, lo);
            Eh[gid] = hi; El[gid] = lo;
        }
    } else {
        if (bid == 1280 && tid == 0) *cnt = 0;
        const int t = (bid - 1280) * 256 + tid;
        const int gw = t >> 6, lane = t & 63;
        const float4 v = ((const float4*)(E + (size_t)gw * D_DIM))[lane];
        float s = v.x * v.x + v.y * v.y + v.z * v.z + v.w * v.w;
#pragma unroll
        for (int off = 32; off; off >>= 1) s += __shfl_down(s, off, 64);
        if (lane == 0) esqb[gw] = s + 1024.0f;
    }
}

// ---------------------------------------------------------------------------
// Pass 1: 1-product (xh*eh) screen, quantized-key top-2 (pure u32 lattice).
// BM=128: 128-row X block (64 KB hi) staged to LDS once; 2x2 wave grid
// (wr,wc) -- the two wr-waves of a wc column read IDENTICAL E addresses
// (Eb independent of wr), so the second wave L1-hits and block count per
// strip halves: E L2 traffic 2.05 GB -> 1.02 GB (R6 diagnosis: E-delivery
// path through L1/TA+L2 at ~19 B/cy/CU was the oversubscribed resource).
// Per-wave body identical to verified R6: per half-tile, batch-16 E loads
// into statically-indexed b[16] (no rotation/cond-copies -- R3/R4 spill
// lesson), then 32 straight-line MFMAs under counted vmcnt, setprio-wrapped.
// Registers identical to R6 (acc 64 AGPR, lattice 64, b[16]): no spill.
// LDS 66 KB -> 2 blocks/CU (occupancy same as R6's measured 19.9%).
// ---------------------------------------------------------------------------
__global__ __launch_bounds__(256, 2)
void vq_pass1(const uint4* __restrict__ Xh, const uint4* __restrict__ Eh,
              const float* __restrict__ esqb, uint2* __restrict__ res) {
    __shared__ uint4 sXh[4096];      // [Lg(32)][r(128)], 64 KB
    __shared__ uint2 slot[2][128];   // [wc][row], 2 KB

    const int tid  = threadIdx.x;
    const int lane = tid & 63, wv = tid >> 6;
    const int wr = wv >> 1, wc = wv & 1;
    const int l31  = lane & 31, lh = lane >> 5;
    const int bid  = blockIdx.x;
    const int bx = bid & 255, strip = bid >> 8;   // strip-chunked: co-resident
    const int cs0 = strip * 2048;                 // blocks share one E strip

    // ---- stage X hi (128 rows x 256 d) once ----
    // LDS slot s = i*256 + wv*64 + lane  ->  Lg = s>>7, r = s&127.
    // global: Xh[(2bx + (wv&1))*2048 + (2i + (wv>>1))*64 + lane]
#pragma unroll
    for (int i = 0; i < 16; ++i)
        gl_lds16(Xh + (size_t)(2 * bx + (wv & 1)) * 2048 + (2 * i + (wv >> 1)) * 64 + lane,
                 &sXh[i * 256 + (wv << 6)]);
    __syncthreads();

    unsigned best[2][16], best2[2][16];
#pragma unroll
    for (int ti = 0; ti < 2; ++ti)
#pragma unroll
        for (int r = 0; r < 16; ++r) { best[ti][r] = 0xFFFFFFFFu; best2[ti][r] = 0xFFFFFFFFu; }

    f32x16 acc[2][2];
    const int arow = wr * 64 + l31;          // A-frag row base (ti adds 32)

#pragma unroll 1
    for (int ct = 0; ct < 16; ++ct) {        // 128-code tiles
        // E base for this wave's 64-code column; independent of wr -> the
        // wr=0/wr=1 pair reads identical granules (L1 reuse).
        const uint4* __restrict__ Eb =
            Eh + (size_t)(strip * 8 + (ct >> 1)) * 8192 + (ct & 1) * 128 + wc * 64 + l31;

        // hoist epilogue operands: no VMEM wait at epilogue start
        const int code0 = cs0 + ct * 128 + wc * 64 + l31;
        const float eb0 = esqb[code0] * 128.0f;        // (e_sq+1024)*128
        const float eb1 = esqb[code0 + 32] * 128.0f;

#pragma unroll
        for (int ti = 0; ti < 2; ++ti)
#pragma unroll
            for (int tj = 0; tj < 2; ++tj)
#pragma unroll
                for (int i = 0; i < 16; ++i) acc[ti][tj][i] = 0.0f;

#pragma unroll 1
        for (int h = 0; h < 2; ++h) {        // half-tiles of 8 k-steps
            const int kb = h * 8;
            // batch-issue all 16 E-granule loads of this half-tile
            f16x8 b[16];
#pragma unroll
            for (int j = 0; j < 8; ++j) {
                const int Lg = (kb + j) * 2 + lh;
                b[j * 2]     = __builtin_bit_cast(f16x8, Eb[Lg * 256]);
                b[j * 2 + 1] = __builtin_bit_cast(f16x8, Eb[Lg * 256 + 32]);
            }
            // 32 straight-line MFMAs drain the batch under counted vmcnt
            __builtin_amdgcn_s_setprio(1);
#pragma unroll
            for (int k = 0; k < 8; ++k) {
                const int Lg = (kb + k) * 2 + lh;
                const f16x8 a0 = __builtin_bit_cast(f16x8, sXh[Lg * 128 + arow]);
                const f16x8 a1 = __builtin_bit_cast(f16x8, sXh[Lg * 128 + arow + 32]);
                acc[0][0] = MFMA32(a0, b[k * 2],     acc[0][0]);
                acc[0][1] = MFMA32(a0, b[k * 2 + 1], acc[0][1]);
                acc[1][0] = MFMA32(a1, b[k * 2],     acc[1][0]);
                acc[1][1] = MFMA32(a1, b[k * 2 + 1], acc[1][1]);
            }
            __builtin_amdgcn_s_setprio(0);
        }

        // epilogue: keyed top-2 lattice update (order-free)
#pragma unroll
        for (int tj = 0; tj < 2; ++tj) {
            const unsigned code = (unsigned)(code0 + tj * 32);
            const float eb128 = tj ? eb1 : eb0;
#pragma unroll
            for (int ti = 0; ti < 2; ++ti)
#pragma unroll
                for (int r = 0; r < 16; ++r) {
                    const float dq = fmaf(-256.0f, acc[ti][tj][r], eb128);
                    const unsigned q   = (unsigned)dq;          // < 2^19
                    const unsigned key = (q << 13) + code;
                    // invariant best<=best2: new best2 = median(key,best,best2)
                    unsigned nb2;
                    asm("v_med3_u32 %0, %1, %2, %3"
                        : "=v"(nb2)
                        : "v"(key), "v"(best[ti][r]), "v"(best2[ti][r]));
                    best2[ti][r] = nb2;
                    best[ti][r]  = key < best[ti][r] ? key : best[ti][r];
                }
        }
    }

    // butterfly over 32 code-lanes (exact top-2 merge, u32)
#pragma unroll
    for (int ti = 0; ti < 2; ++ti)
#pragma unroll
        for (int r = 0; r < 16; ++r) {
            unsigned b1 = best[ti][r], b2 = best2[ti][r];
#pragma unroll
            for (int m = 16; m >= 1; m >>= 1) {
                const unsigned o1 = (unsigned)__shfl_xor((int)b1, m, 32);
                const unsigned o2 = (unsigned)__shfl_xor((int)b2, m, 32);
                const unsigned t  = b1 > o1 ? b1 : o1;
                b1 = b1 < o1 ? b1 : o1;
                const unsigned m2 = b2 < o2 ? b2 : o2;
                b2 = m2 < t ? m2 : t;
            }
            if (l31 == 0) {
                const int row = wr * 64 + ti * 32 + (r & 3) + 8 * (r >> 2) + 4 * lh;
                slot[wc][row] = make_uint2(b1, b2);
            }
        }

    __syncthreads();
    if (tid < 128) {
        const uint2 A = slot[0][tid], B = slot[1][tid];
        const unsigned t  = A.x > B.x ? A.x : B.x;
        const unsigned b1 = A.x < B.x ? A.x : B.x;
        const unsigned m2 = A.y < B.y ? A.y : B.y;
        const unsigned b2 = m2 < t ? m2 : t;
        res[(size_t)strip * N_ROWS + bx * 128 + tid] = make_uint2(b1, b2);
    }
}

// ---------------------------------------------------------------------------
// Merge 4 strips (exact keyed top-2): clean rows -> out; ambiguous -> list.
// ---------------------------------------------------------------------------
__global__ void merge_kernel(const uint2* __restrict__ res,
                             unsigned long long* __restrict__ res0,
                             int* __restrict__ out,
                             int* __restrict__ cnt, int* __restrict__ list) {
    const int row = blockIdx.x * 256 + threadIdx.x;
    unsigned b1 = 0xFFFFFFFFu, b2 = 0xFFFFFFFFu;
#pragma unroll
    for (int s = 0; s < 4; ++s) {
        const uint2 v = res[(size_t)s * N_ROWS + row];
        const unsigned t = b1 > v.x ? b1 : v.x;
        b1 = b1 < v.x ? b1 : v.x;
        const unsigned m2 = b2 < v.y ? b2 : v.y;
        b2 = m2 < t ? m2 : t;
    }
    out[row] = (int)(b1 & 8191u);
    if ((b2 >> 13) - (b1 >> 13) < TQ) {
        const int p = atomicAdd(cnt, 1);
        list[p] = row;
        res0[row] = ~0ull;
    }
}

// ---------------------------------------------------------------------------
// Refine: flagged rows, exact 3-product over all codes (verified structure).
// Block = 32 gathered rows x 1024-code strip (grid 1024 x 8, uniform exit).
// A rows converted from raw fp32 on the fly (same RTN split as prep).
// ---------------------------------------------------------------------------
__global__ __launch_bounds__(256, 1)
void refine_kernel(const float* __restrict__ X,
                   const uint4* __restrict__ Eh, const uint4* __restrict__ El,
                   const float* __restrict__ esqb, const int* __restrict__ cnt,
                   const int* __restrict__ list, unsigned long long* __restrict__ res0) {
    __shared__ int  rows_s[32];
    __shared__ uint4 sAh[1024], sAl[1024];   // 32 KB

    const int n = *cnt;
    const int base = blockIdx.x * 32;
    if (base >= n) return;                   // block-uniform
    const int tid = threadIdx.x;
    if (tid < 32) { const int j = base + tid; rows_s[tid] = list[j < n ? j : base]; }
    __syncthreads();

    // gather + split A: granule slot Lg (0..31) x row slot rr (0..31)
#pragma unroll
    for (int jj = 0; jj < 4; ++jj) {
        const int gg = jj * 256 + tid, Lg = gg >> 5, rr = gg & 31;
        const int row = rows_s[rr];
        const float* p = X + (size_t)row * D_DIM + Lg * 8;
        const float4 a = *(const float4*)p, b = *(const float4*)(p + 4);
        uint4 hi, lo; cvt_rtn(a, b, hi, lo);
        sAh[Lg * 32 + rr] = hi; sAl[Lg * 32 + rr] = lo;
    }
    __syncthreads();

    const int lane = tid & 63, wv = tid >> 6, l31 = lane & 31, lh = lane >> 5;
    const int cbase = blockIdx.y * 1024 + wv * 256;

    float bestv[16]; int besti[16];
#pragma unroll
    for (int r = 0; r < 16; ++r) { bestv[r] = 3.0e38f; besti[r] = 0; }

#pragma unroll 1
    for (int ps = 0; ps < 2; ++ps) {         // 2 passes of 128 codes
        const int c0 = cbase + ps * 128;
        f32x16 acc[4];
#pragma unroll
        for (int tj = 0; tj < 4; ++tj)
#pragma unroll
            for (int i = 0; i < 16; ++i) acc[tj][i] = 0.0f;

#pragma unroll
        for (int ks = 0; ks < 16; ++ks) {
            const int Lg = ks * 2 + lh;
            f16x8 b0[4], b1[4];
#pragma unroll
            for (int tj = 0; tj < 4; ++tj) {
                const int c = c0 + tj * 32 + l31;
                const int eg = (c >> 8) * 8192 + Lg * 256 + (c & 255);
                b0[tj] = __builtin_bit_cast(f16x8, Eh[eg]);
                b1[tj] = __builtin_bit_cast(f16x8, El[eg]);
            }
            const f16x8 a0 = __builtin_bit_cast(f16x8, sAh[Lg * 32 + l31]);
            const f16x8 a1 = __builtin_bit_cast(f16x8, sAl[Lg * 32 + l31]);
#pragma unroll
            for (int tj = 0; tj < 4; ++tj) acc[tj] = MFMA32(a1, b0[tj], acc[tj]);
#pragma unroll
            for (int tj = 0; tj < 4; ++tj) acc[tj] = MFMA32(a0, b1[tj], acc[tj]);
#pragma unroll
            for (int tj = 0; tj < 4; ++tj) acc[tj] = MFMA32(a0, b0[tj], acc[tj]);
        }

#pragma unroll
        for (int tj = 0; tj < 4; ++tj) {
            const int c = c0 + tj * 32 + l31;
            const float eb = esqb[c];
#pragma unroll
            for (int r = 0; r < 16; ++r) {
                const float dv = fmaf(-2.0f, acc[tj][r], eb);
                if (dv < bestv[r]) { bestv[r] = dv; besti[r] = c; }
            }
        }
    }

#pragma unroll
    for (int r = 0; r < 16; ++r) {
        float v = bestv[r]; int bi = besti[r];
#pragma unroll
        for (int m = 16; m >= 1; m >>= 1) {
            const float ov = __shfl_xor(v, m, 32);
            const int   oi = __shfl_xor(bi, m, 32);
            if (ov < v || (ov == v && oi < bi)) { v = ov; bi = oi; }
        }
        if (l31 == 0) {
            const int rl = (r & 3) + 8 * (r >> 2) + 4 * lh;   // 0..31
            atomicMin(&res0[rows_s[rl]],
                      ((unsigned long long)__float_as_uint(v) << 32) | (unsigned)bi);
        }
    }
}

// ---------------------------------------------------------------------------
__global__ void finalize_kernel(const unsigned long long* __restrict__ res0,
                                const int* __restrict__ cnt, const int* __restrict__ list,
                                int* __restrict__ out) {
    const int i = blockIdx.x * 256 + threadIdx.x;
    if (i < *cnt) {
        const int row = list[i];
        out[row] = (int)(res0[row] & 0xFFFFFFFFull);
    }
}

// ---------------------------------------------------------------------------
// Fallback (round-4 verified): in-loop split, for small ws_size.
// ---------------------------------------------------------------------------
__global__ void prologue_fb(const float* __restrict__ E, float* __restrict__ esqb,
                            unsigned long long* __restrict__ packed) {
    const int t = blockIdx.x * 256 + threadIdx.x;
    if (t < N_ROWS) packed[t] = ~0ull;
    const int gw = t >> 6, lane = t & 63;
    const float4 v = ((const float4*)(E + (size_t)gw * D_DIM))[lane];
    float s = v.x * v.x + v.y * v.y + v.z * v.z + v.w * v.w;
#pragma unroll
    for (int off = 32; off; off >>= 1) s += __shfl_down(s, off, 64);
    if (lane == 0) esqb[gw] = s + 1024.0f;
}

__global__ __launch_bounds__(256, 2)
void vq_mfma_fallback(const float* __restrict__ X, const float* __restrict__ E,
                      const float* __restrict__ esqb,
                      unsigned long long* __restrict__ packed) {
    __shared__ uint4 fXh[128 * 8], fXl[128 * 8];
    __shared__ uint4 fEh[128 * 8], fEl[128 * 8];
    __shared__ float fEsq[2048];

    const int tid  = threadIdx.x;
    const int lane = tid & 63;
    const int wv   = tid >> 6;
    const int wr   = wv >> 1, wc = wv & 1;
    const int l31  = lane & 31;
    const int lh   = lane >> 5;
    const int row0 = blockIdx.x * 128;
    const int cs0  = blockIdx.y * 2048;

#pragma unroll
    for (int i = 0; i < 8; ++i) fEsq[tid + 256 * i] = esqb[cs0 + tid + 256 * i];

    const int sr = tid >> 3, sg = tid & 7;

    float best[2][16]; int bidx[2][16];
#pragma unroll
    for (int ti = 0; ti < 2; ++ti)
#pragma unroll
        for (int r = 0; r < 16; ++r) { best[ti][r] = 3.0e38f; bidx[ti][r] = 0; }

    f32x16 acc[2][2];

#pragma unroll 1
    for (int ct = 0; ct < 16; ++ct) {
#pragma unroll
        for (int ti = 0; ti < 2; ++ti)
#pragma unroll
            for (int tj = 0; tj < 2; ++tj)
#pragma unroll
                for (int i = 0; i < 16; ++i) acc[ti][tj][i] = 0.0f;

#pragma unroll 1
        for (int dc = 0; dc < 4; ++dc) {
            __syncthreads();
#pragma unroll
            for (int i = 0; i < 4; ++i) {
                const int r = 32 * i + sr;
                const float* p = X + (size_t)(row0 + r) * D_DIM + dc * 64 + sg * 8;
                const float4 a = *(const float4*)p, b = *(const float4*)(p + 4);
                uint4 hi, lo; cvt_granule(a, b, hi, lo);
                const int o = r * 8 + (sg ^ (r & 7));
                fXh[o] = hi; fXl[o] = lo;
            }
#pragma unroll
            for (int i = 0; i < 4; ++i) {
                const int r = 32 * i + sr;
                const float* p = E + (size_t)(cs0 + ct * 128 + r) * D_DIM + dc * 64 + sg * 8;
                const float4 a = *(const float4*)p, b = *(const float4*)(p + 4);
                uint4 hi, lo; cvt_granule(a, b, hi, lo);
                const int o = r * 8 + (sg ^ (r & 7));
                fEh[o] = hi; fEl[o] = lo;
            }
            __syncthreads();

#pragma unroll
            for (int s = 0; s < 4; ++s) {
                const int gi = s * 2 + lh;
                f16x8 axh[2], axl[2], beh[2], bel[2];
#pragma unroll
                for (int ti = 0; ti < 2; ++ti) {
                    const int r = wr * 64 + ti * 32 + l31;
                    const int o = r * 8 + (gi ^ (r & 7));
                    axh[ti] = __builtin_bit_cast(f16x8, fXh[o]);
                    axl[ti] = __builtin_bit_cast(f16x8, fXl[o]);
                }
#pragma unroll
                for (int tj = 0; tj < 2; ++tj) {
                    const int c = wc * 64 + tj * 32 + l31;
                    const int o = c * 8 + (gi ^ (c & 7));
                    beh[tj] = __builtin_bit_cast(f16x8, fEh[o]);
                    bel[tj] = __builtin_bit_cast(f16x8, fEl[o]);
                }
#pragma unroll
                for (int ti = 0; ti < 2; ++ti)
#pragma unroll
                    for (int tj = 0; tj < 2; ++tj) {
                        acc[ti][tj] = MFMA32(axl[ti], beh[tj], acc[ti][tj]);
                        acc[ti][tj] = MFMA32(axh[ti], bel[tj], acc[ti][tj]);
                        acc[ti][tj] = MFMA32(axh[ti], beh[tj], acc[ti][tj]);
                    }
            }
        }

#pragma unroll
        for (int tj = 0; tj < 2; ++tj) {
            const int cloc = ct * 128 + wc * 64 + tj * 32 + l31;
            const float eb = fEsq[cloc];
            const int  code = cs0 + cloc;
#pragma unroll
            for (int ti = 0; ti < 2; ++ti)
#pragma unroll
                for (int r = 0; r < 16; ++r) {
                    const float dv = fmaf(-2.0f, acc[ti][tj][r], eb);
                    if (dv < best[ti][r]) { best[ti][r] = dv; bidx[ti][r] = code; }
                }
        }
    }

#pragma unroll
    for (int ti = 0; ti < 2; ++ti)
#pragma unroll
        for (int r = 0; r < 16; ++r) {
            float b = best[ti][r]; int bi = bidx[ti][r];
#pragma unroll
            for (int m = 16; m >= 1; m >>= 1) {
                const float ov = __shfl_xor(b, m, 32);
                const int   oi = __shfl_xor(bi, m, 32);
                if (ov < b || (ov == b && oi < bi)) { b = ov; bi = oi; }
            }
            if (l31 == 0) {
                const int row = row0 + wr * 64 + ti * 32 + (r & 3) + 8 * (r >> 2) + 4 * lh;
                const unsigned long long p =
                    ((unsigned long long)__float_as_uint(b) << 32) | (unsigned)bi;
                atomicMin(&packed[row], p);
            }
        }
}

__global__ void finish_fb(const unsigned long long* __restrict__ packed,
                          int* __restrict__ out) {
    const int i = blockIdx.x * 256 + threadIdx.x;
    out[i] = (int)(unsigned)(packed[i] & 0xffffffffull);
}

// ---------------------------------------------------------------------------
extern "C" void kernel_launch(void* const* d_in, const int* in_sizes, int n_in,
                              void* d_out, int out_size, void* d_ws, size_t ws_size,
                              hipStream_t stream) {
    const float* X = (const float*)d_in[0];    // [32768, 256]
    const float* E = (const float*)d_in[1];    // [8192, 256]
    char* ws = (char*)d_ws;
    int* out = (int*)d_out;

    float* esqb = (float*)ws;                                    // 32 KB @ 0
    uint2* res  = (uint2*)(ws + 32768);                          // 1 MB (4 strips)
    unsigned long long* res0 = (unsigned long long*)(ws + 1081344); // 256 KB
    int* cnt  = (int*)(ws + 1343488);                            // 16 B
    int* list = (int*)(ws + 1343504);                            // 128 KB
    const size_t base = 1572864;                                 // 1.5 MB
    const size_t szX  = (size_t)N_ROWS * D_DIM * 2;              // 16 MB (hi only)
    const size_t szE  = (size_t)K_CODES * D_DIM * 2;             // 4 MB per half
    const size_t need = base + szX + 2 * szE;                    // ~25.5 MB

    if (ws_size >= need) {
        uint4* Xh = (uint4*)(ws + base);
        uint4* Eh = (uint4*)(ws + base + szX);
        uint4* El = (uint4*)(ws + base + szX + szE);
        prep_kernel<<<dim3(3328), dim3(256), 0, stream>>>(X, E, Xh, Eh, El, esqb, cnt);
        vq_pass1<<<dim3(1024), dim3(256), 0, stream>>>(Xh, Eh, esqb, res);
        merge_kernel<<<dim3(N_ROWS / 256), dim3(256), 0, stream>>>(res, res0, out, cnt, list);
        refine_kernel<<<dim3(1024, 8), dim3(256), 0, stream>>>(X, Eh, El, esqb,
                                                               cnt, list, res0);
        finalize_kernel<<<dim3(N_ROWS / 256), dim3(256), 0, stream>>>(res0, cnt, list, out);
    } else {
        unsigned long long* packed = (unsigned long long*)(ws + 32768);
        prologue_fb<<<dim3(2048), dim3(256), 0, stream>>>(E, esqb, packed);
        vq_mfma_fallback<<<dim3(N_ROWS / 128, 4), dim3(256), 0, stream>>>(X, E, esqb, packed);
        finish_fb<<<dim3(N_ROWS / 256), dim3(256), 0, stream>>>(packed, out);
    }
}